// Round 15
// baseline (353.515 us; speedup 1.0000x reference)
//
#include <hip/hip_runtime.h>
#include <stdint.h>

// DecLayer: ProteinMPNN-style decoder layer. B=4,N=2048,K=48,H=IN=128.
// R15 = R14 with k_edge re-shaped: 256 threads / 4 waves, each wave computes
// TWO col-groups (w, w+4) per A-fragment read -> wave-wide LDS A-reads halved
// (384->192 per node). Weights persistent in regs (32 frags, 128 regs) -- no
// wpack, no bf16 hvW11 (the two R13 suspects). k_pre/k_node/k_ffn unchanged.

typedef __attribute__((ext_vector_type(8))) short bf16x8;
typedef __attribute__((ext_vector_type(4))) float f32x4;
typedef __attribute__((ext_vector_type(4))) float vf4;
typedef __attribute__((ext_vector_type(2))) float vf2;

#define MFMA16(a,b,c) __builtin_amdgcn_mfma_f32_16x16x32_bf16((a),(b),(c),0,0,0)
#define PITCH 17   // uint4 per tile row (272B): bank shift 4/row, b128-aligned

__device__ __forceinline__ float bf2f(uint16_t u){
  union { uint32_t i; float f; } v; v.i = ((uint32_t)u) << 16; return v.f;
}
__device__ __forceinline__ uint32_t cvtpk(float lo, float hi){
  uint32_t r; asm("v_cvt_pk_bf16_f32 %0, %1, %2" : "=v"(r) : "v"(lo), "v"(hi));
  return r;
}
__device__ __forceinline__ uint16_t f2bf1(float x){ return (uint16_t)cvtpk(x, x); }
__device__ __forceinline__ uint4 pk8v(vf4 a, vf4 b){
  uint4 v; v.x=cvtpk(a[0],a[1]); v.y=cvtpk(a[2],a[3]);
  v.z=cvtpk(b[0],b[1]); v.w=cvtpk(b[2],b[3]); return v;
}
__device__ __forceinline__ float geluf(float x){
  float u = 0.7978845608028654f * x * fmaf(0.044715f, x*x, 1.0f);
  float e = __builtin_amdgcn_exp2f(2.8853900817779268f * u);
  float r = __builtin_amdgcn_rcpf(1.0f + e);
  return fmaf(-x, r, x);
}
template<int CTRL>
__device__ __forceinline__ float dpp_add(float x){
  int s = __builtin_amdgcn_update_dpp(0, __builtin_bit_cast(int, x), CTRL, 0xF, 0xF, true);
  return x + __builtin_bit_cast(float, s);
}
__device__ __forceinline__ float red16(float x){
  x = dpp_add<0x121>(x); x = dpp_add<0x122>(x);
  x = dpp_add<0x124>(x); x = dpp_add<0x128>(x);
  return x;
}
__device__ __forceinline__ bf16x8 wfragf(const float* __restrict__ W, int ncols,
                                         int k0, int col, int g){
  const float* p = W + (size_t)(k0 + g*8)*ncols + col;
  bf16x8 f;
#pragma unroll
  for (int j=0;j<8;j++) f[j] = (short)f2bf1(p[j*ncols]);
  return f;
}
__device__ __forceinline__ bf16x8 afrag(const uint4* tile, int row, int s, int g){
  return *(const bf16x8*)&tile[row*PITCH + 4*s + g];
}
__device__ __forceinline__ void st_m(uint4* tile, int row, int col, uint16_t val){
  ((uint16_t*)tile)[row*(PITCH*8) + col] = val;
}

// ---------------- kernel 0: hvW1 = bf16(hV) @ bf16(W1[0:128,:]) ----------------
__global__ __launch_bounds__(512) void k_pre(
  const float* __restrict__ hV, const float* __restrict__ W1,
  float* __restrict__ hvW1)
{
  const int tid = threadIdx.x;
  const int w = tid>>6, lane = tid&63, g = lane>>4, l15 = lane&15;
  const int col = w*16 + l15;
  const int node0 = blockIdx.x*16;
  bf16x8 Wf[4], A[4];
#pragma unroll
  for (int s=0;s<4;s++) Wf[s] = wfragf(W1,128,32*s,col,g);
#pragma unroll
  for (int s=0;s<4;s++){
    const float* p = hV + (size_t)(node0 + l15)*128 + 32*s + 8*g;
    uint4 t = pk8v(*(const vf4*)p, *(const vf4*)(p+4));
    A[s] = __builtin_bit_cast(bf16x8, t);
  }
  f32x4 acc = {0,0,0,0};
#pragma unroll
  for (int s=0;s<4;s++) acc = MFMA16(A[s], Wf[s], acc);
#pragma unroll
  for (int r=0;r<4;r++) hvW1[(size_t)(node0 + 4*g + r)*128 + col] = acc[r];
}

// ---------------- kernel 1: edge-message MLP + masked sum + LN1 ----------------
__global__ __launch_bounds__(512) void k_node(
  const float* __restrict__ hV, const float* __restrict__ hE,
  const float* __restrict__ mAtt, const float* __restrict__ hvW1,
  const float* __restrict__ W1, const float* __restrict__ B1,
  const float* __restrict__ W2, const float* __restrict__ B2,
  const float* __restrict__ W3, const float* __restrict__ B3,
  const float* __restrict__ LG1, const float* __restrict__ LB1,
  uint16_t* __restrict__ x1b)
{
  __shared__ uint4 Ab[2][48*PITCH];
  __shared__ uint4 Cb[48*PITCH];
  __shared__ float maskb[48];
  __shared__ float dhb[128];

  const int tid = threadIdx.x;
  const int w = tid >> 6, lane = tid & 63, g = lane >> 4, l15 = lane & 15;
  const int col = w*16 + l15;
  const int row0 = tid>>4, cir = tid&15, row1 = 32 + (tid>>4);

  bf16x8 W1e[4], W2f[4], W3f[4];
#pragma unroll
  for (int s=0;s<4;s++) W1e[s] = wfragf(W1,128,128+32*s,col,g);
#pragma unroll
  for (int s=0;s<4;s++) W2f[s] = wfragf(W2,128,32*s,col,g);
#pragma unroll
  for (int s=0;s<4;s++) W3f[s] = wfragf(W3,128,32*s,col,g);
  const float b1c = B1[col], b2c = B2[col], b3c = B3[col];
  float lg0 = 0, lg1 = 0, lb0 = 0, lb1 = 0;
  if (tid < 64){ lg0 = LG1[2*tid]; lg1 = LG1[2*tid+1]; lb0 = LB1[2*tid]; lb1 = LB1[2*tid+1]; }

  vf4 sr0, sr1, sr2, sr3; float mk = 0.f, hv1;
  {
    const int node = blockIdx.x*8;
    const float* hb = hE + (size_t)node*6144;
    sr0 = __builtin_nontemporal_load((const vf4*)(hb + tid*8));
    sr1 = __builtin_nontemporal_load((const vf4*)(hb + tid*8 + 4));
    if (tid < 256){
      sr2 = __builtin_nontemporal_load((const vf4*)(hb + 4096 + tid*8));
      sr3 = __builtin_nontemporal_load((const vf4*)(hb + 4096 + tid*8 + 4));
    }
    if (tid >= 64 && tid < 112) mk = mAtt[(size_t)node*48 + (tid-64)];
    hv1 = hvW1[(size_t)node*128 + col];
    Ab[0][row0*PITCH + cir] = pk8v(sr0, sr1);
    if (tid < 256) Ab[0][row1*PITCH + cir] = pk8v(sr2, sr3);
    if (tid >= 64 && tid < 112) maskb[tid-64] = mk;
  }
  __syncthreads();

  for (int it=0; it<8; ++it){
    const int node = blockIdx.x*8 + it;
    const uint4* Ac = Ab[it&1];
    uint4* Acm = Ab[it&1];
    uint4* An  = Ab[(it&1)^1];
    f32x4 ahv = {hv1, hv1, hv1, hv1};
#pragma unroll
    for (int t=0;t<3;t++){
      f32x4 acc = ahv;
      int row = 16*t + l15;
#pragma unroll
      for (int s=0;s<4;s++) acc = MFMA16(afrag(Ac,row,s,g), W1e[s], acc);
#pragma unroll
      for (int r=0;r<4;r++) st_m(Cb, 16*t+4*g+r, col, f2bf1(geluf(acc[r]+b1c)));
    }
    __syncthreads();
#pragma unroll
    for (int t=0;t<3;t++){
      f32x4 acc = {0,0,0,0};
      int row = 16*t + l15;
#pragma unroll
      for (int s=0;s<4;s++) acc = MFMA16(afrag(Cb,row,s,g), W2f[s], acc);
#pragma unroll
      for (int r=0;r<4;r++) st_m(Acm, 16*t+4*g+r, col, f2bf1(geluf(acc[r]+b2c)));
    }
    __syncthreads();
    if (it < 7){
      const float* hb = hE + (size_t)(node+1)*6144;
      sr0 = __builtin_nontemporal_load((const vf4*)(hb + tid*8));
      sr1 = __builtin_nontemporal_load((const vf4*)(hb + tid*8 + 4));
      if (tid < 256){
        sr2 = __builtin_nontemporal_load((const vf4*)(hb + 4096 + tid*8));
        sr3 = __builtin_nontemporal_load((const vf4*)(hb + 4096 + tid*8 + 4));
      }
      if (tid >= 64 && tid < 112) mk = mAtt[(size_t)(node+1)*48 + (tid-64)];
      hv1 = hvW1[(size_t)(node+1)*128 + col];
    }
    float pp = 0.f;
#pragma unroll
    for (int t=0;t<3;t++){
      f32x4 acc = {0,0,0,0};
      int row = 16*t + l15;
#pragma unroll
      for (int s=0;s<4;s++) acc = MFMA16(afrag(Ac,row,s,g), W3f[s], acc);
#pragma unroll
      for (int r=0;r<4;r++) pp += maskb[16*t+4*g+r] * (acc[r] + b3c);
    }
    pp += __shfl_xor(pp, 16);
    pp += __shfl_xor(pp, 32);
    if (lane < 16) dhb[col] = pp * (1.f/30.f);
    __syncthreads();
    if (tid < 64){
      int c0 = 2*tid, c1 = c0+1;
      float2 hv2 = *(const float2*)(hV + (size_t)node*128 + c0);
      float xa = hv2.x + dhb[c0];
      float xc = hv2.y + dhb[c1];
      float s1 = xa + xc, s2 = xa*xa + xc*xc;
      s1 = red16(s1); s2 = red16(s2);
      s1 += __shfl_xor(s1,16); s2 += __shfl_xor(s2,16);
      s1 += __shfl_xor(s1,32); s2 += __shfl_xor(s2,32);
      float mu = s1 * (1.0f/128.0f);
      float var = fmaxf(s2 * (1.0f/128.0f) - mu*mu, 0.f);
      float rstd = __builtin_amdgcn_rsqf(var + 1e-5f);
      float ya = (xa-mu)*rstd*lg0 + lb0;
      float yc = (xc-mu)*rstd*lg1 + lb1;
      ((uint32_t*)x1b)[(size_t)node*64 + tid] = cvtpk(ya, yc);
    }
    if (it < 7){
      An[row0*PITCH + cir] = pk8v(sr0, sr1);
      if (tid < 256) An[row1*PITCH + cir] = pk8v(sr2, sr3);
      if (tid >= 64 && tid < 112) maskb[tid-64] = mk;
    }
    __syncthreads();
  }
}

// ---------------- kernel 2: fused FFN + LN2 + mask_V (+ optional hvW11) ------
template<bool HV11>
__global__ __launch_bounds__(512) void k_ffn(
  const uint16_t* __restrict__ x1b,
  const float* __restrict__ Win, const float* __restrict__ Bin,
  const float* __restrict__ Wout, const float* __restrict__ Bout,
  const float* __restrict__ W11,
  const float* __restrict__ LG2, const float* __restrict__ LB2,
  const float* __restrict__ maskV,
  float* __restrict__ outV, uint16_t* __restrict__ outVb,
  float* __restrict__ hvW11)
{
  __shared__ uint4 lh[16*65];     // hidden tile; later reused as bf16 h_V tile
  __shared__ float xb[16*129];

  const int tid = threadIdx.x;
  const int w = tid>>6, lane = tid&63, g = lane>>4, l15 = lane&15;
  const int colo = w*16 + l15;

  bf16x8 WiF[4][4], WoF[16], W11s[4];
#pragma unroll
  for (int s=0;s<4;s++)
#pragma unroll
    for (int c=0;c<4;c++) WiF[s][c] = wfragf(Win,512,32*s, w*64 + c*16 + l15, g);
#pragma unroll
  for (int s=0;s<16;s++) WoF[s] = wfragf(Wout,128,32*s, colo, g);
  if (HV11){
#pragma unroll
    for (int s=0;s<4;s++) W11s[s] = wfragf(W11,128,32*s,colo,g);
  }
  float binc[4];
#pragma unroll
  for (int c=0;c<4;c++) binc[c] = Bin[w*64 + c*16 + l15];
  const float boutc = Bout[colo];
  const float lg0 = LG2[2*lane], lg1 = LG2[2*lane+1];
  const float lb0 = LB2[2*lane], lb1 = LB2[2*lane+1];

  for (int it=0; it<2; ++it){
    const int node0 = (blockIdx.x*2 + it)*16;
    bf16x8 A[4];
#pragma unroll
    for (int s=0;s<4;s++) A[s] = *(const bf16x8*)(x1b + (size_t)(node0 + l15)*128 + 32*s + 8*g);
#pragma unroll
    for (int c=0;c<4;c++){
      f32x4 acc = {0,0,0,0};
#pragma unroll
      for (int s=0;s<4;s++) acc = MFMA16(A[s], WiF[s][c], acc);
      int colh = w*64 + c*16 + l15;
#pragma unroll
      for (int r=0;r<4;r++){
        int row = 4*g + r;
        ((uint16_t*)lh)[row*(65*8) + colh] = f2bf1(geluf(acc[r] + binc[c]));
      }
    }
    __syncthreads();
    f32x4 acc = {0,0,0,0};
#pragma unroll
    for (int s=0;s<16;s++){
      bf16x8 a = *(const bf16x8*)&lh[l15*65 + 4*s + g];
      acc = MFMA16(a, WoF[s], acc);
    }
#pragma unroll
    for (int r=0;r<4;r++){
      int row = 4*g + r;
      xb[row*129 + colo] = bf2f(x1b[(size_t)(node0+row)*128 + colo]) + acc[r] + boutc;
    }
    __syncthreads();
#pragma unroll
    for (int rr=0; rr<2; ++rr){
      int row = w + rr*8;
      int c0 = 2*lane;
      float xa = xb[row*129 + c0], xc = xb[row*129 + c0 + 1];
      float s1 = xa + xc, s2 = xa*xa + xc*xc;
      s1 = red16(s1); s2 = red16(s2);
      s1 += __shfl_xor(s1,16); s2 += __shfl_xor(s2,16);
      s1 += __shfl_xor(s1,32); s2 += __shfl_xor(s2,32);
      float mu = s1*(1.0f/128.0f);
      float var = fmaxf(s2*(1.0f/128.0f)-mu*mu, 0.f);
      float rstd = __builtin_amdgcn_rsqf(var + 1e-5f);
      float mv = maskV[node0 + row];
      float ya = ((xa-mu)*rstd*lg0 + lb0) * mv;
      float yc = ((xc-mu)*rstd*lg1 + lb1) * mv;
      vf2 o2; o2[0] = ya; o2[1] = yc;
      __builtin_nontemporal_store(o2, (vf2*)outV + (size_t)(node0+row)*64 + lane);
      uint32_t pk = cvtpk(ya, yc);
      if (outVb)
        ((uint32_t*)outVb)[(size_t)(node0+row)*64 + lane] = pk;
      if (HV11)
        ((uint32_t*)lh)[row*132 + lane] = pk;   // bf16 h_V tile, pitch 132 u32
    }
    __syncthreads();
    if (HV11){
      f32x4 a2 = {0,0,0,0};
#pragma unroll
      for (int s=0;s<4;s++){
        bf16x8 a = *(const bf16x8*)&((uint32_t*)lh)[l15*132 + 16*s + 4*g];
        a2 = MFMA16(a, W11s[s], a2);
      }
#pragma unroll
      for (int r=0;r<4;r++)
        hvW11[(size_t)(node0 + 4*g + r)*128 + colo] = a2[r];
      __syncthreads();
    }
  }
}

// ---------------- kernel 3 (fast): 256-thr, 4 waves x 2 col-groups ----------
__global__ __launch_bounds__(256) void k_edge3(
  const float* __restrict__ hE, const int* __restrict__ Eidx,
  const uint16_t* __restrict__ hV2b, const float* __restrict__ hvW11,
  const float* __restrict__ W11, const float* __restrict__ B11,
  const float* __restrict__ W12, const float* __restrict__ B12,
  const float* __restrict__ W13, const float* __restrict__ B13,
  const float* __restrict__ LG3, const float* __restrict__ LB3,
  float* __restrict__ outE)
{
  __shared__ uint4 Ab[2][48*PITCH];   // staged hE (dbuf) -> LN3 residual
  __shared__ uint4 Bb[48*PITCH];      // neighbors -> layer2 out
  __shared__ uint4 Cb[48*PITCH];      // layer1 out -> layer3 out

  const int tid = threadIdx.x;               // 0..255
  const int w = tid>>6, lane = tid&63, g = lane>>4, l15 = lane&15;
  const int col0 = w*16 + l15;               // wave's first col-group
  // persistent weights: 2 col-groups x {W11e,W11n,W12,W13} x 4 k-slices
  bf16x8 We[2][4], Wn[2][4], W2f[2][4], W3f[2][4];
#pragma unroll
  for (int h=0;h<2;h++){
    int ch = col0 + 64*h;
#pragma unroll
    for (int s=0;s<4;s++){
      We[h][s]  = wfragf(W11,128, 128+32*s, ch, g);
      Wn[h][s]  = wfragf(W11,128, 256+32*s, ch, g);
      W2f[h][s] = wfragf(W12,128,     32*s, ch, g);
      W3f[h][s] = wfragf(W13,128,     32*s, ch, g);
    }
  }
  const float b11a = B11[col0], b11q = B11[col0+64];
  const float b12a = B12[col0], b12q = B12[col0+64];
  const float b13a = B13[col0], b13q = B13[col0+64];
  const float lg0 = LG3[2*lane], lg1 = LG3[2*lane+1];
  const float lb0 = LB3[2*lane], lb1 = LB3[2*lane+1];

  vf4 sr[6]; int gi[3]; float hva, hvq;
  { // prologue: node 0
    const int node = blockIdx.x*8;
    const int bb = (node>>11)<<11;
    const float* hb = hE + (size_t)node*6144;
#pragma unroll
    for (int q=0;q<3;q++){
      int c = tid + 256*q;
      sr[2*q]   = __builtin_nontemporal_load((const vf4*)(hb + (size_t)c*8));
      sr[2*q+1] = __builtin_nontemporal_load((const vf4*)(hb + (size_t)c*8 + 4));
      gi[q] = Eidx[(size_t)node*48 + (c>>4)];
    }
    hva = hvW11[(size_t)node*128 + col0];
    hvq = hvW11[(size_t)node*128 + col0 + 64];
    uint4 gq[3];
#pragma unroll
    for (int q=0;q<3;q++){
      int c = tid + 256*q;
      gq[q] = *(const uint4*)(hV2b + (size_t)(bb + gi[q])*128 + (c&15)*8);
    }
#pragma unroll
    for (int q=0;q<3;q++){
      int c = tid + 256*q;
      int row = c>>4, cir = c&15;
      Ab[0][row*PITCH + cir] = pk8v(sr[2*q], sr[2*q+1]);
      Bb[row*PITCH + cir] = gq[q];
    }
  }
  __syncthreads();

  for (int it=0; it<8; ++it){
    const int node = blockIdx.x*8 + it;
    const uint4* Ac = Ab[it&1];
    uint4* An = Ab[(it&1)^1];
    // ---------- layer 1: Ac + Bb -> Cb (acc init = hvW11) ----------
#pragma unroll
    for (int t=0;t<3;t++){
      int row = 16*t + l15;
      bf16x8 ae[4], bn[4];
#pragma unroll
      for (int s=0;s<4;s++){ ae[s] = afrag(Ac,row,s,g); bn[s] = afrag(Bb,row,s,g); }
#pragma unroll
      for (int h=0;h<2;h++){
        float hv = h ? hvq : hva;
        f32x4 acc = {hv,hv,hv,hv};
#pragma unroll
        for (int s=0;s<4;s++) acc = MFMA16(ae[s], We[h][s], acc);
#pragma unroll
        for (int s=0;s<4;s++) acc = MFMA16(bn[s], Wn[h][s], acc);
        float bs = h ? b11q : b11a;
        int ch = col0 + 64*h;
#pragma unroll
        for (int r=0;r<4;r++) st_m(Cb, 16*t+4*g+r, ch, f2bf1(geluf(acc[r]+bs)));
      }
    }
    __syncthreads();
    // ---------- layer 2: Cb -> Bb ----------
#pragma unroll
    for (int t=0;t<3;t++){
      int row = 16*t + l15;
      bf16x8 a[4];
#pragma unroll
      for (int s=0;s<4;s++) a[s] = afrag(Cb,row,s,g);
#pragma unroll
      for (int h=0;h<2;h++){
        f32x4 acc = {0,0,0,0};
#pragma unroll
        for (int s=0;s<4;s++) acc = MFMA16(a[s], W2f[h][s], acc);
        float bs = h ? b12q : b12a;
        int ch = col0 + 64*h;
#pragma unroll
        for (int r=0;r<4;r++) st_m(Bb, 16*t+4*g+r, ch, f2bf1(geluf(acc[r]+bs)));
      }
    }
    __syncthreads();
    // ---------- layer 3: Bb -> Cb; prefetch next hE/idx/hv first ----------
    if (it < 7){
      const float* hb = hE + (size_t)(node+1)*6144;
#pragma unroll
      for (int q=0;q<3;q++){
        int c = tid + 256*q;
        sr[2*q]   = __builtin_nontemporal_load((const vf4*)(hb + (size_t)c*8));
        sr[2*q+1] = __builtin_nontemporal_load((const vf4*)(hb + (size_t)c*8 + 4));
        gi[q] = Eidx[(size_t)(node+1)*48 + (c>>4)];
      }
      hva = hvW11[(size_t)(node+1)*128 + col0];
      hvq = hvW11[(size_t)(node+1)*128 + col0 + 64];
    }
#pragma unroll
    for (int t=0;t<3;t++){
      int row = 16*t + l15;
      bf16x8 a[4];
#pragma unroll
      for (int s=0;s<4;s++) a[s] = afrag(Bb,row,s,g);
#pragma unroll
      for (int h=0;h<2;h++){
        f32x4 acc = {0,0,0,0};
#pragma unroll
        for (int s=0;s<4;s++) acc = MFMA16(a[s], W3f[h][s], acc);
        float bs = h ? b13q : b13a;
        int ch = col0 + 64*h;
#pragma unroll
        for (int r=0;r<4;r++) st_m(Cb, 16*t+4*g+r, ch, f2bf1(acc[r]+bs));
      }
    }
    __syncthreads();
    // ---------- LN3 (+ gathers, then stage next node) ----------
    uint4 gq[3];
    if (it < 7){
      const int bb2 = ((node+1)>>11)<<11;
#pragma unroll
      for (int q=0;q<3;q++){
        int c = tid + 256*q;
        gq[q] = *(const uint4*)(hV2b + (size_t)(bb2 + gi[q])*128 + (c&15)*8);
      }
    }
#pragma unroll
    for (int rr=0; rr<12; ++rr){
      int row = 4*rr + w;
      uint32_t pe = ((const uint32_t*)Ac)[row*(PITCH*4) + lane];
      uint32_t pv = ((const uint32_t*)Cb)[row*(PITCH*4) + lane];
      float xa = bf2f((uint16_t)(pe & 0xffff)) + bf2f((uint16_t)(pv & 0xffff));
      float xc = bf2f((uint16_t)(pe >> 16))    + bf2f((uint16_t)(pv >> 16));
      float s1 = xa + xc, s2 = xa*xa + xc*xc;
      s1 = red16(s1); s2 = red16(s2);
      s1 += __shfl_xor(s1,16); s2 += __shfl_xor(s2,16);
      s1 += __shfl_xor(s1,32); s2 += __shfl_xor(s2,32);
      float mu = s1*(1.0f/128.0f);
      float var = fmaxf(s2*(1.0f/128.0f)-mu*mu, 0.f);
      float rstd = __builtin_amdgcn_rsqf(var+1e-5f);
      float ya = (xa-mu)*rstd*lg0 + lb0;
      float yc = (xc-mu)*rstd*lg1 + lb1;
      vf2 o2; o2[0] = ya; o2[1] = yc;
      __builtin_nontemporal_store(o2, (vf2*)outE + ((size_t)node*48 + row)*64 + lane);
    }
    if (it < 7){
#pragma unroll
      for (int q=0;q<3;q++){
        int c = tid + 256*q;
        int row = c>>4, cir = c&15;
        An[row*PITCH + cir] = pk8v(sr[2*q], sr[2*q+1]);
        Bb[row*PITCH + cir] = gq[q];
      }
    }
    __syncthreads();
  }
}

// ---------------- kernel 3 (safe fallback) ----------------
__global__ __launch_bounds__(512) void k_edge_safe(
  const float* __restrict__ hE, const int* __restrict__ Eidx,
  const float* __restrict__ hV2f,
  const float* __restrict__ W11, const float* __restrict__ B11,
  const float* __restrict__ W12, const float* __restrict__ B12,
  const float* __restrict__ W13, const float* __restrict__ B13,
  const float* __restrict__ LG3, const float* __restrict__ LB3,
  float* __restrict__ outE)
{
  __shared__ uint4 Ab[2][48*PITCH];
  __shared__ uint4 Bb[48*PITCH];
  __shared__ uint4 Cb[48*PITCH];
  __shared__ uint4 hvb[16];

  const int tid = threadIdx.x;
  const int w = tid>>6, lane = tid&63, g = lane>>4, l15 = lane&15;
  const int col = w*16 + l15;
  const int row0 = tid>>4, cir = tid&15, row1 = 32 + (tid>>4);

  bf16x8 Ws[4], W11e[4], W11n[4], W12f[4], W13f[4];
#pragma unroll
  for (int s=0;s<4;s++) Ws[s]   = wfragf(W11,128,     32*s,col,g);
#pragma unroll
  for (int s=0;s<4;s++) W11e[s] = wfragf(W11,128, 128+32*s,col,g);
#pragma unroll
  for (int s=0;s<4;s++) W11n[s] = wfragf(W11,128, 256+32*s,col,g);
#pragma unroll
  for (int s=0;s<4;s++) W12f[s] = wfragf(W12,128,     32*s,col,g);
#pragma unroll
  for (int s=0;s<4;s++) W13f[s] = wfragf(W13,128,     32*s,col,g);
  const float b11c = B11[col], b12c = B12[col], b13c = B13[col];

  vf4 sr0, sr1, sr2, sr3; int gi0, gi1; uint4 hvr;
  {
    const int node = blockIdx.x*8;
    const int bb = (node >> 11) << 11;
    const float* hb = hE + (size_t)node*6144;
    sr0 = __builtin_nontemporal_load((const vf4*)(hb + tid*8));
    sr1 = __builtin_nontemporal_load((const vf4*)(hb + tid*8 + 4));
    if (tid < 256){
      sr2 = __builtin_nontemporal_load((const vf4*)(hb + 4096 + tid*8));
      sr3 = __builtin_nontemporal_load((const vf4*)(hb + 4096 + tid*8 + 4));
    }
    gi0 = Eidx[(size_t)node*48 + (tid>>4)];
    gi1 = (tid < 256) ? Eidx[(size_t)node*48 + 32 + (tid>>4)] : 0;
    uint4 gq0, gq1;
    {
      const float* p0 = hV2f + (size_t)(bb + gi0)*128 + (tid&15)*8;
      gq0 = pk8v(*(const vf4*)p0, *(const vf4*)(p0+4));
      if (tid < 256){
        const float* p1 = hV2f + (size_t)(bb + gi1)*128 + (tid&15)*8;
        gq1 = pk8v(*(const vf4*)p1, *(const vf4*)(p1+4));
      }
      if (tid < 16){
        const float* p = hV2f + (size_t)node*128 + tid*8;
        hvr = pk8v(*(const vf4*)p, *(const vf4*)(p+4));
      }
    }
    Ab[0][row0*PITCH + cir] = pk8v(sr0, sr1);
    Bb[row0*PITCH + cir] = gq0;
    if (tid < 256){
      Ab[0][row1*PITCH + cir] = pk8v(sr2, sr3);
      Bb[row1*PITCH + cir] = gq1;
    }
    if (tid < 16) hvb[tid] = hvr;
  }
  __syncthreads();

  for (int it=0; it<8; ++it){
    const int node = blockIdx.x*8 + it;
    const uint4* Ac = Ab[it&1];
    uint4* An = Ab[(it&1)^1];
    f32x4 ahv = {0,0,0,0};
#pragma unroll
    for (int s=0;s<4;s++) ahv = MFMA16(*(const bf16x8*)&hvb[4*s+g], Ws[s], ahv);
#pragma unroll
    for (int t=0;t<3;t++){
      f32x4 acc = ahv;
      int row = 16*t + l15;
#pragma unroll
      for (int s=0;s<4;s++) acc = MFMA16(afrag(Ac,row,s,g), W11e[s], acc);
#pragma unroll
      for (int s=0;s<4;s++) acc = MFMA16(afrag(Bb,row,s,g), W11n[s], acc);
#pragma unroll
      for (int r=0;r<4;r++) st_m(Cb, 16*t+4*g+r, col, f2bf1(geluf(acc[r]+b11c)));
    }
    __syncthreads();
#pragma unroll
    for (int t=0;t<3;t++){
      f32x4 acc = {0,0,0,0};
      int row = 16*t + l15;
#pragma unroll
      for (int s=0;s<4;s++) acc = MFMA16(afrag(Cb,row,s,g), W12f[s], acc);
#pragma unroll
      for (int r=0;r<4;r++) st_m(Bb, 16*t+4*g+r, col, f2bf1(geluf(acc[r]+b12c)));
    }
    __syncthreads();
    if (it < 7){
      const float* hb = hE + (size_t)(node+1)*6144;
      sr0 = __builtin_nontemporal_load((const vf4*)(hb + tid*8));
      sr1 = __builtin_nontemporal_load((const vf4*)(hb + tid*8 + 4));
      if (tid < 256){
        sr2 = __builtin_nontemporal_load((const vf4*)(hb + 4096 + tid*8));
        sr3 = __builtin_nontemporal_load((const vf4*)(hb + 4096 + tid*8 + 4));
      }
      gi0 = Eidx[(size_t)(node+1)*48 + (tid>>4)];
      gi1 = (tid < 256) ? Eidx[(size_t)(node+1)*48 + 32 + (tid>>4)] : 0;
    }
#pragma unroll
    for (int t=0;t<3;t++){
      f32x4 acc = {0,0,0,0};
      int row = 16*t + l15;
#pragma unroll
      for (int s=0;s<4;s++) acc = MFMA16(afrag(Bb,row,s,g), W13f[s], acc);
#pragma unroll
      for (int r=0;r<4;r++) st_m(Cb, 16*t+4*g+r, col, f2bf1(acc[r]+b13c));
    }
    __syncthreads();
    uint4 gq0, gq1;
    if (it < 7){
      const int bb2 = ((node+1) >> 11) << 11;
      const float* p0 = hV2f + (size_t)(bb2 + gi0)*128 + (tid&15)*8;
      gq0 = pk8v(*(const vf4*)p0, *(const vf4*)(p0+4));
      if (tid < 256){
        const float* p1 = hV2f + (size_t)(bb2 + gi1)*128 + (tid&15)*8;
        gq1 = pk8v(*(const vf4*)p1, *(const vf4*)(p1+4));
      }
      if (tid < 16){
        const float* p = hV2f + (size_t)(node+1)*128 + tid*8;
        hvr = pk8v(*(const vf4*)p, *(const vf4*)(p+4));
      }
    }
#pragma unroll
    for (int rr=0; rr<6; ++rr){
      int row = w + rr*8;
      int c0 = 2*lane;
      uint32_t pe = ((const uint32_t*)Ac)[row*(PITCH*4) + lane];
      uint32_t pv = ((const uint32_t*)Cb)[row*(PITCH*4) + lane];
      float xa = bf2f((uint16_t)(pe & 0xffff)) + bf2f((uint16_t)(pv & 0xffff));
      float xc = bf2f((uint16_t)(pe >> 16))    + bf2f((uint16_t)(pv >> 16));
      float s1 = xa + xc, s2 = xa*xa + xc*xc;
      s1 = red16(s1); s2 = red16(s2);
      s1 += __shfl_xor(s1,16); s2 += __shfl_xor(s2,16);
      s1 += __shfl_xor(s1,32); s2 += __shfl_xor(s2,32);
      float mu = s1*(1.0f/128.0f);
      float var = fmaxf(s2*(1.0f/128.0f)-mu*mu, 0.f);
      float rstd = __builtin_amdgcn_rsqf(var+1e-5f);
      float ya = (xa-mu)*rstd*LG3[c0] + LB3[c0];
      float yc = (xc-mu)*rstd*LG3[c0+1] + LB3[c0+1];
      vf2 o2; o2[0] = ya; o2[1] = yc;
      __builtin_nontemporal_store(o2, (vf2*)outE + ((size_t)node*48 + row)*64 + lane);
    }
    if (it < 7){
      An[row0*PITCH + cir] = pk8v(sr0, sr1);
      Bb[row0*PITCH + cir] = gq0;
      if (tid < 256){
        An[row1*PITCH + cir] = pk8v(sr2, sr3);
        Bb[row1*PITCH + cir] = gq1;
      }
      if (tid < 16) hvb[tid] = hvr;
    }
    __syncthreads();
  }
}

extern "C" void kernel_launch(void* const* d_in, const int* in_sizes, int n_in,
                              void* d_out, int out_size, void* d_ws, size_t ws_size,
                              hipStream_t stream){
  const float* hV   = (const float*)d_in[0];
  const float* hE   = (const float*)d_in[1];
  const float* mV   = (const float*)d_in[2];
  const int*   Eidx = (const int*)d_in[3];
  const float* mAtt = (const float*)d_in[4];
  const float* W1 = (const float*)d_in[5];  const float* B1 = (const float*)d_in[6];
  const float* W2 = (const float*)d_in[7];  const float* B2 = (const float*)d_in[8];
  const float* W3 = (const float*)d_in[9];  const float* B3 = (const float*)d_in[10];
  const float* W11 = (const float*)d_in[11]; const float* B11 = (const float*)d_in[12];
  const float* W12 = (const float*)d_in[13]; const float* B12 = (const float*)d_in[14];
  const float* W13 = (const float*)d_in[15]; const float* B13 = (const float*)d_in[16];
  const float* Win = (const float*)d_in[17]; const float* Bin = (const float*)d_in[18];
  const float* Wout= (const float*)d_in[19]; const float* Bout= (const float*)d_in[20];
  const float* LG1 = (const float*)d_in[21]; const float* LB1 = (const float*)d_in[22];
  const float* LG2 = (const float*)d_in[23]; const float* LB2 = (const float*)d_in[24];
  const float* LG3 = (const float*)d_in[25]; const float* LB3 = (const float*)d_in[26];

  float* outV = (float*)d_out;                     // [B*N*H] f32
  float* outE = outV + (size_t)1048576;            // [B*N*K*IN] f32
  uint16_t* x1b = (uint16_t*)(outE + (size_t)1048576);   // [4,6MB) of outE region
  float*    hvW1 = outE + (size_t)1572864;         // [6,10MB): dead after k_node

  const bool bf16g = ws_size >= ((size_t)2<<20);
  const bool fast  = ws_size >= ((size_t)6<<20);
  uint16_t* outVb = bf16g ? (uint16_t*)d_ws : nullptr;   // [0,2MB) of ws
  float*    hvW11 = fast ? (float*)((char*)d_ws + ((size_t)2<<20)) : nullptr; // [2,6MB)

  hipLaunchKernelGGL(k_pre, dim3(512), dim3(512), 0, stream, hV, W1, hvW1);
  hipLaunchKernelGGL(k_node, dim3(1024), dim3(512), 0, stream,
      hV, hE, mAtt, hvW1, W1,B1, W2,B2, W3,B3, LG1,LB1, x1b);
  if (fast){
    hipLaunchKernelGGL((k_ffn<true>), dim3(256), dim3(512), 0, stream,
        x1b, Win,Bin, Wout,Bout, W11, LG2,LB2, mV, outV, outVb, hvW11);
    hipLaunchKernelGGL(k_edge3, dim3(1024), dim3(256), 0, stream,
        hE, Eidx, outVb, hvW11, W11,B11, W12,B12, W13,B13, LG3,LB3, outE);
  } else {
    hipLaunchKernelGGL((k_ffn<false>), dim3(256), dim3(512), 0, stream,
        x1b, Win,Bin, Wout,Bout, W11, LG2,LB2, mV, outV, nullptr, nullptr);
    hipLaunchKernelGGL(k_edge_safe, dim3(1024), dim3(512), 0, stream,
        hE, Eidx, outV, W11,B11, W12,B12, W13,B13, LG3,LB3, outE);
  }
}

// Round 16
// 306.888 us; speedup vs baseline: 1.1519x; 1.1519x over previous
//
#include <hip/hip_runtime.h>
#include <stdint.h>

// DecLayer: ProteinMPNN-style decoder layer. B=4,N=2048,K=48,H=IN=128.
// R16 = R14 (known-good 318us) + bf16-hE handoff: k_node writes its staged
// bf16 hE tiles to hEb (48MB in d_ws, guarded ws>=54MB); k_edge_fast<true>
// stages via plain uint4 copies (half read bytes, no cvt VALU). Numerics
// identical (same pk8v values). R15's 2-col-group kernel reverted: its 128
// AGPR weights + 132 VGPR = 260 regs -> 1 wave/SIMD -> occupancy loss.

typedef __attribute__((ext_vector_type(8))) short bf16x8;
typedef __attribute__((ext_vector_type(4))) float f32x4;
typedef __attribute__((ext_vector_type(4))) float vf4;
typedef __attribute__((ext_vector_type(2))) float vf2;
typedef __attribute__((ext_vector_type(4))) unsigned int vu4;

#define MFMA16(a,b,c) __builtin_amdgcn_mfma_f32_16x16x32_bf16((a),(b),(c),0,0,0)
#define PITCH 17   // uint4 per tile row (272B)

__device__ __forceinline__ float bf2f(uint16_t u){
  union { uint32_t i; float f; } v; v.i = ((uint32_t)u) << 16; return v.f;
}
__device__ __forceinline__ uint32_t cvtpk(float lo, float hi){
  uint32_t r; asm("v_cvt_pk_bf16_f32 %0, %1, %2" : "=v"(r) : "v"(lo), "v"(hi));
  return r;
}
__device__ __forceinline__ uint16_t f2bf1(float x){ return (uint16_t)cvtpk(x, x); }
__device__ __forceinline__ uint4 pk8v(vf4 a, vf4 b){
  uint4 v; v.x=cvtpk(a[0],a[1]); v.y=cvtpk(a[2],a[3]);
  v.z=cvtpk(b[0],b[1]); v.w=cvtpk(b[2],b[3]); return v;
}
__device__ __forceinline__ float geluf(float x){
  float u = 0.7978845608028654f * x * fmaf(0.044715f, x*x, 1.0f);
  float e = __builtin_amdgcn_exp2f(2.8853900817779268f * u);
  float r = __builtin_amdgcn_rcpf(1.0f + e);
  return fmaf(-x, r, x);
}
template<int CTRL>
__device__ __forceinline__ float dpp_add(float x){
  int s = __builtin_amdgcn_update_dpp(0, __builtin_bit_cast(int, x), CTRL, 0xF, 0xF, true);
  return x + __builtin_bit_cast(float, s);
}
__device__ __forceinline__ float red16(float x){
  x = dpp_add<0x121>(x); x = dpp_add<0x122>(x);
  x = dpp_add<0x124>(x); x = dpp_add<0x128>(x);
  return x;
}
__device__ __forceinline__ bf16x8 wfragf(const float* __restrict__ W, int ncols,
                                         int k0, int col, int g){
  const float* p = W + (size_t)(k0 + g*8)*ncols + col;
  bf16x8 f;
#pragma unroll
  for (int j=0;j<8;j++) f[j] = (short)f2bf1(p[j*ncols]);
  return f;
}
__device__ __forceinline__ bf16x8 afrag(const uint4* tile, int row, int s, int g){
  return *(const bf16x8*)&tile[row*PITCH + 4*s + g];
}
__device__ __forceinline__ void st_m(uint4* tile, int row, int col, uint16_t val){
  ((uint16_t*)tile)[row*(PITCH*8) + col] = val;
}

// ---------------- kernel 0: hvW1 = bf16(hV) @ bf16(W1[0:128,:]) ----------------
__global__ __launch_bounds__(512) void k_pre(
  const float* __restrict__ hV, const float* __restrict__ W1,
  float* __restrict__ hvW1)
{
  const int tid = threadIdx.x;
  const int w = tid>>6, lane = tid&63, g = lane>>4, l15 = lane&15;
  const int col = w*16 + l15;
  const int node0 = blockIdx.x*16;
  bf16x8 Wf[4], A[4];
#pragma unroll
  for (int s=0;s<4;s++) Wf[s] = wfragf(W1,128,32*s,col,g);
#pragma unroll
  for (int s=0;s<4;s++){
    const float* p = hV + (size_t)(node0 + l15)*128 + 32*s + 8*g;
    uint4 t = pk8v(*(const vf4*)p, *(const vf4*)(p+4));
    A[s] = __builtin_bit_cast(bf16x8, t);
  }
  f32x4 acc = {0,0,0,0};
#pragma unroll
  for (int s=0;s<4;s++) acc = MFMA16(A[s], Wf[s], acc);
#pragma unroll
  for (int r=0;r<4;r++) hvW1[(size_t)(node0 + 4*g + r)*128 + col] = acc[r];
}

// ---------------- kernel 1: edge-message MLP + masked sum + LN1 ----------------
// Also emits bf16 hE tiles to hEb (row-major 48*128 bf16 per node) when non-null.
__global__ __launch_bounds__(512) void k_node(
  const float* __restrict__ hV, const float* __restrict__ hE,
  const float* __restrict__ mAtt, const float* __restrict__ hvW1,
  const float* __restrict__ W1, const float* __restrict__ B1,
  const float* __restrict__ W2, const float* __restrict__ B2,
  const float* __restrict__ W3, const float* __restrict__ B3,
  const float* __restrict__ LG1, const float* __restrict__ LB1,
  uint16_t* __restrict__ x1b, uint16_t* __restrict__ hEb)
{
  __shared__ uint4 Ab[2][48*PITCH];
  __shared__ uint4 Cb[48*PITCH];
  __shared__ float maskb[48];
  __shared__ float dhb[128];

  const int tid = threadIdx.x;
  const int w = tid >> 6, lane = tid & 63, g = lane >> 4, l15 = lane & 15;
  const int col = w*16 + l15;
  const int row0 = tid>>4, cir = tid&15, row1 = 32 + (tid>>4);

  bf16x8 W1e[4], W2f[4], W3f[4];
#pragma unroll
  for (int s=0;s<4;s++) W1e[s] = wfragf(W1,128,128+32*s,col,g);
#pragma unroll
  for (int s=0;s<4;s++) W2f[s] = wfragf(W2,128,32*s,col,g);
#pragma unroll
  for (int s=0;s<4;s++) W3f[s] = wfragf(W3,128,32*s,col,g);
  const float b1c = B1[col], b2c = B2[col], b3c = B3[col];
  float lg0 = 0, lg1 = 0, lb0 = 0, lb1 = 0;
  if (tid < 64){ lg0 = LG1[2*tid]; lg1 = LG1[2*tid+1]; lb0 = LB1[2*tid]; lb1 = LB1[2*tid+1]; }

  vf4 sr0, sr1, sr2, sr3; float mk = 0.f, hv1;
  {
    const int node = blockIdx.x*8;
    const float* hb = hE + (size_t)node*6144;
    sr0 = __builtin_nontemporal_load((const vf4*)(hb + tid*8));
    sr1 = __builtin_nontemporal_load((const vf4*)(hb + tid*8 + 4));
    if (tid < 256){
      sr2 = __builtin_nontemporal_load((const vf4*)(hb + 4096 + tid*8));
      sr3 = __builtin_nontemporal_load((const vf4*)(hb + 4096 + tid*8 + 4));
    }
    if (tid >= 64 && tid < 112) mk = mAtt[(size_t)node*48 + (tid-64)];
    hv1 = hvW1[(size_t)node*128 + col];
    uint4 v0 = pk8v(sr0, sr1);
    Ab[0][row0*PITCH + cir] = v0;
    if (hEb)
      __builtin_nontemporal_store(*(vu4*)&v0, (vu4*)hEb + (size_t)node*768 + tid);
    if (tid < 256){
      uint4 v1 = pk8v(sr2, sr3);
      Ab[0][row1*PITCH + cir] = v1;
      if (hEb)
        __builtin_nontemporal_store(*(vu4*)&v1, (vu4*)hEb + (size_t)node*768 + 512 + tid);
    }
    if (tid >= 64 && tid < 112) maskb[tid-64] = mk;
  }
  __syncthreads();

  for (int it=0; it<8; ++it){
    const int node = blockIdx.x*8 + it;
    const uint4* Ac = Ab[it&1];
    uint4* Acm = Ab[it&1];
    uint4* An  = Ab[(it&1)^1];
    f32x4 ahv = {hv1, hv1, hv1, hv1};
#pragma unroll
    for (int t=0;t<3;t++){
      f32x4 acc = ahv;
      int row = 16*t + l15;
#pragma unroll
      for (int s=0;s<4;s++) acc = MFMA16(afrag(Ac,row,s,g), W1e[s], acc);
#pragma unroll
      for (int r=0;r<4;r++) st_m(Cb, 16*t+4*g+r, col, f2bf1(geluf(acc[r]+b1c)));
    }
    __syncthreads();
#pragma unroll
    for (int t=0;t<3;t++){
      f32x4 acc = {0,0,0,0};
      int row = 16*t + l15;
#pragma unroll
      for (int s=0;s<4;s++) acc = MFMA16(afrag(Cb,row,s,g), W2f[s], acc);
#pragma unroll
      for (int r=0;r<4;r++) st_m(Acm, 16*t+4*g+r, col, f2bf1(geluf(acc[r]+b2c)));
    }
    __syncthreads();
    if (it < 7){
      const float* hb = hE + (size_t)(node+1)*6144;
      sr0 = __builtin_nontemporal_load((const vf4*)(hb + tid*8));
      sr1 = __builtin_nontemporal_load((const vf4*)(hb + tid*8 + 4));
      if (tid < 256){
        sr2 = __builtin_nontemporal_load((const vf4*)(hb + 4096 + tid*8));
        sr3 = __builtin_nontemporal_load((const vf4*)(hb + 4096 + tid*8 + 4));
      }
      if (tid >= 64 && tid < 112) mk = mAtt[(size_t)(node+1)*48 + (tid-64)];
      hv1 = hvW1[(size_t)(node+1)*128 + col];
    }
    float pp = 0.f;
#pragma unroll
    for (int t=0;t<3;t++){
      f32x4 acc = {0,0,0,0};
      int row = 16*t + l15;
#pragma unroll
      for (int s=0;s<4;s++) acc = MFMA16(afrag(Ac,row,s,g), W3f[s], acc);
#pragma unroll
      for (int r=0;r<4;r++) pp += maskb[16*t+4*g+r] * (acc[r] + b3c);
    }
    pp += __shfl_xor(pp, 16);
    pp += __shfl_xor(pp, 32);
    if (lane < 16) dhb[col] = pp * (1.f/30.f);
    __syncthreads();
    if (tid < 64){
      int c0 = 2*tid, c1 = c0+1;
      float2 hv2 = *(const float2*)(hV + (size_t)node*128 + c0);
      float xa = hv2.x + dhb[c0];
      float xc = hv2.y + dhb[c1];
      float s1 = xa + xc, s2 = xa*xa + xc*xc;
      s1 = red16(s1); s2 = red16(s2);
      s1 += __shfl_xor(s1,16); s2 += __shfl_xor(s2,16);
      s1 += __shfl_xor(s1,32); s2 += __shfl_xor(s2,32);
      float mu = s1 * (1.0f/128.0f);
      float var = fmaxf(s2 * (1.0f/128.0f) - mu*mu, 0.f);
      float rstd = __builtin_amdgcn_rsqf(var + 1e-5f);
      float ya = (xa-mu)*rstd*lg0 + lb0;
      float yc = (xc-mu)*rstd*lg1 + lb1;
      ((uint32_t*)x1b)[(size_t)node*64 + tid] = cvtpk(ya, yc);
    }
    if (it < 7){
      uint4 v0 = pk8v(sr0, sr1);
      An[row0*PITCH + cir] = v0;
      if (hEb)
        __builtin_nontemporal_store(*(vu4*)&v0, (vu4*)hEb + (size_t)(node+1)*768 + tid);
      if (tid < 256){
        uint4 v1 = pk8v(sr2, sr3);
        An[row1*PITCH + cir] = v1;
        if (hEb)
          __builtin_nontemporal_store(*(vu4*)&v1, (vu4*)hEb + (size_t)(node+1)*768 + 512 + tid);
      }
      if (tid >= 64 && tid < 112) maskb[tid-64] = mk;
    }
    __syncthreads();
  }
}

// ---------------- kernel 2: fused FFN + LN2 + mask_V (+ optional hvW11) ------
template<bool HV11>
__global__ __launch_bounds__(512) void k_ffn(
  const uint16_t* __restrict__ x1b,
  const float* __restrict__ Win, const float* __restrict__ Bin,
  const float* __restrict__ Wout, const float* __restrict__ Bout,
  const float* __restrict__ W11,
  const float* __restrict__ LG2, const float* __restrict__ LB2,
  const float* __restrict__ maskV,
  float* __restrict__ outV, uint16_t* __restrict__ outVb,
  float* __restrict__ hvW11)
{
  __shared__ uint4 lh[16*65];
  __shared__ float xb[16*129];

  const int tid = threadIdx.x;
  const int w = tid>>6, lane = tid&63, g = lane>>4, l15 = lane&15;
  const int colo = w*16 + l15;

  bf16x8 WiF[4][4], WoF[16], W11s[4];
#pragma unroll
  for (int s=0;s<4;s++)
#pragma unroll
    for (int c=0;c<4;c++) WiF[s][c] = wfragf(Win,512,32*s, w*64 + c*16 + l15, g);
#pragma unroll
  for (int s=0;s<16;s++) WoF[s] = wfragf(Wout,128,32*s, colo, g);
  if (HV11){
#pragma unroll
    for (int s=0;s<4;s++) W11s[s] = wfragf(W11,128,32*s,colo,g);
  }
  float binc[4];
#pragma unroll
  for (int c=0;c<4;c++) binc[c] = Bin[w*64 + c*16 + l15];
  const float boutc = Bout[colo];
  const float lg0 = LG2[2*lane], lg1 = LG2[2*lane+1];
  const float lb0 = LB2[2*lane], lb1 = LB2[2*lane+1];

  for (int it=0; it<2; ++it){
    const int node0 = (blockIdx.x*2 + it)*16;
    bf16x8 A[4];
#pragma unroll
    for (int s=0;s<4;s++) A[s] = *(const bf16x8*)(x1b + (size_t)(node0 + l15)*128 + 32*s + 8*g);
#pragma unroll
    for (int c=0;c<4;c++){
      f32x4 acc = {0,0,0,0};
#pragma unroll
      for (int s=0;s<4;s++) acc = MFMA16(A[s], WiF[s][c], acc);
      int colh = w*64 + c*16 + l15;
#pragma unroll
      for (int r=0;r<4;r++){
        int row = 4*g + r;
        ((uint16_t*)lh)[row*(65*8) + colh] = f2bf1(geluf(acc[r] + binc[c]));
      }
    }
    __syncthreads();
    f32x4 acc = {0,0,0,0};
#pragma unroll
    for (int s=0;s<16;s++){
      bf16x8 a = *(const bf16x8*)&lh[l15*65 + 4*s + g];
      acc = MFMA16(a, WoF[s], acc);
    }
#pragma unroll
    for (int r=0;r<4;r++){
      int row = 4*g + r;
      xb[row*129 + colo] = bf2f(x1b[(size_t)(node0+row)*128 + colo]) + acc[r] + boutc;
    }
    __syncthreads();
#pragma unroll
    for (int rr=0; rr<2; ++rr){
      int row = w + rr*8;
      int c0 = 2*lane;
      float xa = xb[row*129 + c0], xc = xb[row*129 + c0 + 1];
      float s1 = xa + xc, s2 = xa*xa + xc*xc;
      s1 = red16(s1); s2 = red16(s2);
      s1 += __shfl_xor(s1,16); s2 += __shfl_xor(s2,16);
      s1 += __shfl_xor(s1,32); s2 += __shfl_xor(s2,32);
      float mu = s1*(1.0f/128.0f);
      float var = fmaxf(s2*(1.0f/128.0f)-mu*mu, 0.f);
      float rstd = __builtin_amdgcn_rsqf(var + 1e-5f);
      float mv = maskV[node0 + row];
      float ya = ((xa-mu)*rstd*lg0 + lb0) * mv;
      float yc = ((xc-mu)*rstd*lg1 + lb1) * mv;
      vf2 o2; o2[0] = ya; o2[1] = yc;
      __builtin_nontemporal_store(o2, (vf2*)outV + (size_t)(node0+row)*64 + lane);
      uint32_t pk = cvtpk(ya, yc);
      if (outVb)
        ((uint32_t*)outVb)[(size_t)(node0+row)*64 + lane] = pk;
      if (HV11)
        ((uint32_t*)lh)[row*132 + lane] = pk;
    }
    __syncthreads();
    if (HV11){
      f32x4 a2 = {0,0,0,0};
#pragma unroll
      for (int s=0;s<4;s++){
        bf16x8 a = *(const bf16x8*)&((uint32_t*)lh)[l15*132 + 16*s + 4*g];
        a2 = MFMA16(a, W11s[s], a2);
      }
#pragma unroll
      for (int r=0;r<4;r++)
        hvW11[(size_t)(node0 + 4*g + r)*128 + colo] = a2[r];
      __syncthreads();
    }
  }
}

// ---------------- kernel 3 (fast): edge update MLP + LN3 ----------------
// HEB: stage hE from the bf16 hEb buffer (uint4 copies, no cvt);
// else: stage from f32 hE with on-the-fly pack (R14 behavior).
template<bool HEB>
__global__ __launch_bounds__(512) void k_edge_fast(
  const float* __restrict__ hE, const uint16_t* __restrict__ hEb,
  const int* __restrict__ Eidx,
  const uint16_t* __restrict__ hV2b, const float* __restrict__ hvW11,
  const float* __restrict__ W11, const float* __restrict__ B11,
  const float* __restrict__ W12, const float* __restrict__ B12,
  const float* __restrict__ W13, const float* __restrict__ B13,
  const float* __restrict__ LG3, const float* __restrict__ LB3,
  float* __restrict__ outE)
{
  __shared__ uint4 Ab[2][48*PITCH];
  __shared__ uint4 Bb[48*PITCH];
  __shared__ uint4 Cb[48*PITCH];

  const int tid = threadIdx.x;
  const int w = tid>>6, lane = tid&63, g = lane>>4, l15 = lane&15;
  const int col = w*16 + l15;
  const int row0 = tid>>4, cir = tid&15, row1 = 32 + (tid>>4);

  bf16x8 W11e[4], W11n[4], W12f[4], W13f[4];
#pragma unroll
  for (int s=0;s<4;s++) W11e[s] = wfragf(W11,128, 128+32*s,col,g);
#pragma unroll
  for (int s=0;s<4;s++) W11n[s] = wfragf(W11,128, 256+32*s,col,g);
#pragma unroll
  for (int s=0;s<4;s++) W12f[s] = wfragf(W12,128,     32*s,col,g);
#pragma unroll
  for (int s=0;s<4;s++) W13f[s] = wfragf(W13,128,     32*s,col,g);
  const float b11c = B11[col], b12c = B12[col], b13c = B13[col];
  const float lg0 = LG3[2*lane], lg1 = LG3[2*lane+1];
  const float lb0 = LB3[2*lane], lb1 = LB3[2*lane+1];

  vf4 sr0, sr1, sr2, sr3; vu4 su0, su1;
  int gi0, gi1; float hv11;
  {
    const int node = blockIdx.x*8;
    const int bb = (node >> 11) << 11;
    if (HEB){
      su0 = __builtin_nontemporal_load((const vu4*)hEb + (size_t)node*768 + tid);
      if (tid < 256)
        su1 = __builtin_nontemporal_load((const vu4*)hEb + (size_t)node*768 + 512 + tid);
    } else {
      const float* hb = hE + (size_t)node*6144;
      sr0 = __builtin_nontemporal_load((const vf4*)(hb + tid*8));
      sr1 = __builtin_nontemporal_load((const vf4*)(hb + tid*8 + 4));
      if (tid < 256){
        sr2 = __builtin_nontemporal_load((const vf4*)(hb + 4096 + tid*8));
        sr3 = __builtin_nontemporal_load((const vf4*)(hb + 4096 + tid*8 + 4));
      }
    }
    gi0 = Eidx[(size_t)node*48 + (tid>>4)];
    gi1 = (tid < 256) ? Eidx[(size_t)node*48 + 32 + (tid>>4)] : 0;
    hv11 = hvW11[(size_t)node*128 + col];
    uint4 gq0 = *(const uint4*)(hV2b + (size_t)(bb + gi0)*128 + (tid&15)*8);
    uint4 gq1;
    if (tid < 256) gq1 = *(const uint4*)(hV2b + (size_t)(bb + gi1)*128 + (tid&15)*8);
    if (HEB){
      *(vu4*)&Ab[0][row0*PITCH + cir] = su0;
      if (tid < 256) *(vu4*)&Ab[0][row1*PITCH + cir] = su1;
    } else {
      Ab[0][row0*PITCH + cir] = pk8v(sr0, sr1);
      if (tid < 256) Ab[0][row1*PITCH + cir] = pk8v(sr2, sr3);
    }
    Bb[row0*PITCH + cir] = gq0;
    if (tid < 256) Bb[row1*PITCH + cir] = gq1;
  }
  __syncthreads();

  for (int it=0; it<8; ++it){
    const int node = blockIdx.x*8 + it;
    const uint4* Ac = Ab[it&1];
    uint4* An = Ab[(it&1)^1];
    // ---------- layer 1: Ab[cur] + Bb -> Cb (acc init = hvW11) ----------
    f32x4 ahv = {hv11, hv11, hv11, hv11};
#pragma unroll
    for (int t=0;t<3;t++){
      f32x4 acc = ahv;
      int row = 16*t + l15;
#pragma unroll
      for (int s=0;s<4;s++) acc = MFMA16(afrag(Ac,row,s,g), W11e[s], acc);
#pragma unroll
      for (int s=0;s<4;s++) acc = MFMA16(afrag(Bb,row,s,g), W11n[s], acc);
#pragma unroll
      for (int r=0;r<4;r++) st_m(Cb, 16*t+4*g+r, col, f2bf1(geluf(acc[r]+b11c)));
    }
    __syncthreads();
    // ---------- layer 2: Cb -> Bb ----------
#pragma unroll
    for (int t=0;t<3;t++){
      f32x4 acc = {0,0,0,0};
      int row = 16*t + l15;
#pragma unroll
      for (int s=0;s<4;s++) acc = MFMA16(afrag(Cb,row,s,g), W12f[s], acc);
#pragma unroll
      for (int r=0;r<4;r++) st_m(Bb, 16*t+4*g+r, col, f2bf1(geluf(acc[r]+b12c)));
    }
    __syncthreads();
    // ---------- layer 3: Bb -> Cb; issue next loads first ----------
    if (it < 7){
      if (HEB){
        su0 = __builtin_nontemporal_load((const vu4*)hEb + (size_t)(node+1)*768 + tid);
        if (tid < 256)
          su1 = __builtin_nontemporal_load((const vu4*)hEb + (size_t)(node+1)*768 + 512 + tid);
      } else {
        const float* hb = hE + (size_t)(node+1)*6144;
        sr0 = __builtin_nontemporal_load((const vf4*)(hb + tid*8));
        sr1 = __builtin_nontemporal_load((const vf4*)(hb + tid*8 + 4));
        if (tid < 256){
          sr2 = __builtin_nontemporal_load((const vf4*)(hb + 4096 + tid*8));
          sr3 = __builtin_nontemporal_load((const vf4*)(hb + 4096 + tid*8 + 4));
        }
      }
      gi0 = Eidx[(size_t)(node+1)*48 + (tid>>4)];
      gi1 = (tid < 256) ? Eidx[(size_t)(node+1)*48 + 32 + (tid>>4)] : 0;
      hv11 = hvW11[(size_t)(node+1)*128 + col];
    }
#pragma unroll
    for (int t=0;t<3;t++){
      f32x4 acc = {0,0,0,0};
      int row = 16*t + l15;
#pragma unroll
      for (int s=0;s<4;s++) acc = MFMA16(afrag(Bb,row,s,g), W13f[s], acc);
#pragma unroll
      for (int r=0;r<4;r++) st_m(Cb, 16*t+4*g+r, col, f2bf1(acc[r]+b13c));
    }
    __syncthreads();
    // ---------- LN3 (+ issue gathers, then stage next node) ----------
    uint4 gq0, gq1;
    if (it < 7){
      const int bb2 = ((node+1) >> 11) << 11;
      gq0 = *(const uint4*)(hV2b + (size_t)(bb2 + gi0)*128 + (tid&15)*8);
      if (tid < 256) gq1 = *(const uint4*)(hV2b + (size_t)(bb2 + gi1)*128 + (tid&15)*8);
    }
#pragma unroll
    for (int rr=0; rr<6; ++rr){
      int row = w + rr*8;
      int c0 = 2*lane;
      uint32_t pe = ((const uint32_t*)Ac)[row*(PITCH*4) + lane];
      uint32_t pv = ((const uint32_t*)Cb)[row*(PITCH*4) + lane];
      float xa = bf2f((uint16_t)(pe & 0xffff)) + bf2f((uint16_t)(pv & 0xffff));
      float xc = bf2f((uint16_t)(pe >> 16))    + bf2f((uint16_t)(pv >> 16));
      float s1 = xa + xc, s2 = xa*xa + xc*xc;
      s1 = red16(s1); s2 = red16(s2);
      s1 += __shfl_xor(s1,16); s2 += __shfl_xor(s2,16);
      s1 += __shfl_xor(s1,32); s2 += __shfl_xor(s2,32);
      float mu = s1*(1.0f/128.0f);
      float var = fmaxf(s2*(1.0f/128.0f)-mu*mu, 0.f);
      float rstd = __builtin_amdgcn_rsqf(var+1e-5f);
      float ya = (xa-mu)*rstd*lg0 + lb0;
      float yc = (xc-mu)*rstd*lg1 + lb1;
      vf2 o2; o2[0] = ya; o2[1] = yc;
      __builtin_nontemporal_store(o2, (vf2*)outE + ((size_t)node*48 + row)*64 + lane);
    }
    if (it < 7){
      if (HEB){
        *(vu4*)&An[row0*PITCH + cir] = su0;
        if (tid < 256) *(vu4*)&An[row1*PITCH + cir] = su1;
      } else {
        An[row0*PITCH + cir] = pk8v(sr0, sr1);
        if (tid < 256) An[row1*PITCH + cir] = pk8v(sr2, sr3);
      }
      Bb[row0*PITCH + cir] = gq0;
      if (tid < 256) Bb[row1*PITCH + cir] = gq1;
    }
    __syncthreads();
  }
}

// ---------------- kernel 3 (safe fallback) ----------------
__global__ __launch_bounds__(512) void k_edge_safe(
  const float* __restrict__ hE, const int* __restrict__ Eidx,
  const float* __restrict__ hV2f,
  const float* __restrict__ W11, const float* __restrict__ B11,
  const float* __restrict__ W12, const float* __restrict__ B12,
  const float* __restrict__ W13, const float* __restrict__ B13,
  const float* __restrict__ LG3, const float* __restrict__ LB3,
  float* __restrict__ outE)
{
  __shared__ uint4 Ab[2][48*PITCH];
  __shared__ uint4 Bb[48*PITCH];
  __shared__ uint4 Cb[48*PITCH];
  __shared__ uint4 hvb[16];

  const int tid = threadIdx.x;
  const int w = tid>>6, lane = tid&63, g = lane>>4, l15 = lane&15;
  const int col = w*16 + l15;
  const int row0 = tid>>4, cir = tid&15, row1 = 32 + (tid>>4);

  bf16x8 Ws[4], W11e[4], W11n[4], W12f[4], W13f[4];
#pragma unroll
  for (int s=0;s<4;s++) Ws[s]   = wfragf(W11,128,     32*s,col,g);
#pragma unroll
  for (int s=0;s<4;s++) W11e[s] = wfragf(W11,128, 128+32*s,col,g);
#pragma unroll
  for (int s=0;s<4;s++) W11n[s] = wfragf(W11,128, 256+32*s,col,g);
#pragma unroll
  for (int s=0;s<4;s++) W12f[s] = wfragf(W12,128,     32*s,col,g);
#pragma unroll
  for (int s=0;s<4;s++) W13f[s] = wfragf(W13,128,     32*s,col,g);
  const float b11c = B11[col], b12c = B12[col], b13c = B13[col];

  vf4 sr0, sr1, sr2, sr3; int gi0, gi1; uint4 hvr;
  {
    const int node = blockIdx.x*8;
    const int bb = (node >> 11) << 11;
    const float* hb = hE + (size_t)node*6144;
    sr0 = __builtin_nontemporal_load((const vf4*)(hb + tid*8));
    sr1 = __builtin_nontemporal_load((const vf4*)(hb + tid*8 + 4));
    if (tid < 256){
      sr2 = __builtin_nontemporal_load((const vf4*)(hb + 4096 + tid*8));
      sr3 = __builtin_nontemporal_load((const vf4*)(hb + 4096 + tid*8 + 4));
    }
    gi0 = Eidx[(size_t)node*48 + (tid>>4)];
    gi1 = (tid < 256) ? Eidx[(size_t)node*48 + 32 + (tid>>4)] : 0;
    uint4 gq0, gq1;
    {
      const float* p0 = hV2f + (size_t)(bb + gi0)*128 + (tid&15)*8;
      gq0 = pk8v(*(const vf4*)p0, *(const vf4*)(p0+4));
      if (tid < 256){
        const float* p1 = hV2f + (size_t)(bb + gi1)*128 + (tid&15)*8;
        gq1 = pk8v(*(const vf4*)p1, *(const vf4*)(p1+4));
      }
      if (tid < 16){
        const float* p = hV2f + (size_t)node*128 + tid*8;
        hvr = pk8v(*(const vf4*)p, *(const vf4*)(p+4));
      }
    }
    Ab[0][row0*PITCH + cir] = pk8v(sr0, sr1);
    Bb[row0*PITCH + cir] = gq0;
    if (tid < 256){
      Ab[0][row1*PITCH + cir] = pk8v(sr2, sr3);
      Bb[row1*PITCH + cir] = gq1;
    }
    if (tid < 16) hvb[tid] = hvr;
  }
  __syncthreads();

  for (int it=0; it<8; ++it){
    const int node = blockIdx.x*8 + it;
    const uint4* Ac = Ab[it&1];
    uint4* An = Ab[(it&1)^1];
    f32x4 ahv = {0,0,0,0};
#pragma unroll
    for (int s=0;s<4;s++) ahv = MFMA16(*(const bf16x8*)&hvb[4*s+g], Ws[s], ahv);
#pragma unroll
    for (int t=0;t<3;t++){
      f32x4 acc = ahv;
      int row = 16*t + l15;
#pragma unroll
      for (int s=0;s<4;s++) acc = MFMA16(afrag(Ac,row,s,g), W11e[s], acc);
#pragma unroll
      for (int s=0;s<4;s++) acc = MFMA16(afrag(Bb,row,s,g), W11n[s], acc);
#pragma unroll
      for (int r=0;r<4;r++) st_m(Cb, 16*t+4*g+r, col, f2bf1(geluf(acc[r]+b11c)));
    }
    __syncthreads();
#pragma unroll
    for (int t=0;t<3;t++){
      f32x4 acc = {0,0,0,0};
      int row = 16*t + l15;
#pragma unroll
      for (int s=0;s<4;s++) acc = MFMA16(afrag(Cb,row,s,g), W12f[s], acc);
#pragma unroll
      for (int r=0;r<4;r++) st_m(Bb, 16*t+4*g+r, col, f2bf1(geluf(acc[r]+b12c)));
    }
    __syncthreads();
    if (it < 7){
      const float* hb = hE + (size_t)(node+1)*6144;
      sr0 = __builtin_nontemporal_load((const vf4*)(hb + tid*8));
      sr1 = __builtin_nontemporal_load((const vf4*)(hb + tid*8 + 4));
      if (tid < 256){
        sr2 = __builtin_nontemporal_load((const vf4*)(hb + 4096 + tid*8));
        sr3 = __builtin_nontemporal_load((const vf4*)(hb + 4096 + tid*8 + 4));
      }
      gi0 = Eidx[(size_t)(node+1)*48 + (tid>>4)];
      gi1 = (tid < 256) ? Eidx[(size_t)(node+1)*48 + 32 + (tid>>4)] : 0;
    }
#pragma unroll
    for (int t=0;t<3;t++){
      f32x4 acc = {0,0,0,0};
      int row = 16*t + l15;
#pragma unroll
      for (int s=0;s<4;s++) acc = MFMA16(afrag(Bb,row,s,g), W13f[s], acc);
#pragma unroll
      for (int r=0;r<4;r++) st_m(Cb, 16*t+4*g+r, col, f2bf1(acc[r]+b13c));
    }
    __syncthreads();
    uint4 gq0, gq1;
    if (it < 7){
      const int bb2 = ((node+1) >> 11) << 11;
      const float* p0 = hV2f + (size_t)(bb2 + gi0)*128 + (tid&15)*8;
      gq0 = pk8v(*(const vf4*)p0, *(const vf4*)(p0+4));
      if (tid < 256){
        const float* p1 = hV2f + (size_t)(bb2 + gi1)*128 + (tid&15)*8;
        gq1 = pk8v(*(const vf4*)p1, *(const vf4*)(p1+4));
      }
      if (tid < 16){
        const float* p = hV2f + (size_t)(node+1)*128 + tid*8;
        hvr = pk8v(*(const vf4*)p, *(const vf4*)(p+4));
      }
    }
#pragma unroll
    for (int rr=0; rr<6; ++rr){
      int row = w + rr*8;
      int c0 = 2*lane;
      uint32_t pe = ((const uint32_t*)Ac)[row*(PITCH*4) + lane];
      uint32_t pv = ((const uint32_t*)Cb)[row*(PITCH*4) + lane];
      float xa = bf2f((uint16_t)(pe & 0xffff)) + bf2f((uint16_t)(pv & 0xffff));
      float xc = bf2f((uint16_t)(pe >> 16))    + bf2f((uint16_t)(pv >> 16));
      float s1 = xa + xc, s2 = xa*xa + xc*xc;
      s1 = red16(s1); s2 = red16(s2);
      s1 += __shfl_xor(s1,16); s2 += __shfl_xor(s2,16);
      s1 += __shfl_xor(s1,32); s2 += __shfl_xor(s2,32);
      float mu = s1*(1.0f/128.0f);
      float var = fmaxf(s2*(1.0f/128.0f)-mu*mu, 0.f);
      float rstd = __builtin_amdgcn_rsqf(var+1e-5f);
      float ya = (xa-mu)*rstd*LG3[c0] + LB3[c0];
      float yc = (xc-mu)*rstd*LG3[c0+1] + LB3[c0+1];
      vf2 o2; o2[0] = ya; o2[1] = yc;
      __builtin_nontemporal_store(o2, (vf2*)outE + ((size_t)node*48 + row)*64 + lane);
    }
    if (it < 7){
      An[row0*PITCH + cir] = pk8v(sr0, sr1);
      Bb[row0*PITCH + cir] = gq0;
      if (tid < 256){
        An[row1*PITCH + cir] = pk8v(sr2, sr3);
        Bb[row1*PITCH + cir] = gq1;
      }
      if (tid < 16) hvb[tid] = hvr;
    }
    __syncthreads();
  }
}

extern "C" void kernel_launch(void* const* d_in, const int* in_sizes, int n_in,
                              void* d_out, int out_size, void* d_ws, size_t ws_size,
                              hipStream_t stream){
  const float* hV   = (const float*)d_in[0];
  const float* hE   = (const float*)d_in[1];
  const float* mV   = (const float*)d_in[2];
  const int*   Eidx = (const int*)d_in[3];
  const float* mAtt = (const float*)d_in[4];
  const float* W1 = (const float*)d_in[5];  const float* B1 = (const float*)d_in[6];
  const float* W2 = (const float*)d_in[7];  const float* B2 = (const float*)d_in[8];
  const float* W3 = (const float*)d_in[9];  const float* B3 = (const float*)d_in[10];
  const float* W11 = (const float*)d_in[11]; const float* B11 = (const float*)d_in[12];
  const float* W12 = (const float*)d_in[13]; const float* B12 = (const float*)d_in[14];
  const float* W13 = (const float*)d_in[15]; const float* B13 = (const float*)d_in[16];
  const float* Win = (const float*)d_in[17]; const float* Bin = (const float*)d_in[18];
  const float* Wout= (const float*)d_in[19]; const float* Bout= (const float*)d_in[20];
  const float* LG1 = (const float*)d_in[21]; const float* LB1 = (const float*)d_in[22];
  const float* LG2 = (const float*)d_in[23]; const float* LB2 = (const float*)d_in[24];
  const float* LG3 = (const float*)d_in[25]; const float* LB3 = (const float*)d_in[26];

  float* outV = (float*)d_out;                     // [B*N*H] f32
  float* outE = outV + (size_t)1048576;            // [B*N*K*IN] f32
  uint16_t* x1b = (uint16_t*)(outE + (size_t)1048576);   // [4,6MB) of outE region
  float*    hvW1 = outE + (size_t)1572864;         // [6,10MB): dead after k_node

  const bool bf16g = ws_size >= ((size_t)2<<20);
  const bool fast  = ws_size >= ((size_t)6<<20);
  const bool bigws = ws_size >= ((size_t)54<<20);
  uint16_t* outVb = bf16g ? (uint16_t*)d_ws : nullptr;                          // [0,2MB)
  float*    hvW11 = fast ? (float*)((char*)d_ws + ((size_t)2<<20)) : nullptr;   // [2,6MB)
  uint16_t* hEb   = bigws ? (uint16_t*)((char*)d_ws + ((size_t)6<<20)) : nullptr; // [6,54MB)

  hipLaunchKernelGGL(k_pre, dim3(512), dim3(512), 0, stream, hV, W1, hvW1);
  hipLaunchKernelGGL(k_node, dim3(1024), dim3(512), 0, stream,
      hV, hE, mAtt, hvW1, W1,B1, W2,B2, W3,B3, LG1,LB1, x1b, hEb);
  if (fast){
    hipLaunchKernelGGL((k_ffn<true>), dim3(256), dim3(512), 0, stream,
        x1b, Win,Bin, Wout,Bout, W11, LG2,LB2, mV, outV, outVb, hvW11);
    if (bigws)
      hipLaunchKernelGGL((k_edge_fast<true>), dim3(1024), dim3(512), 0, stream,
          hE, hEb, Eidx, outVb, hvW11, W11,B11, W12,B12, W13,B13, LG3,LB3, outE);
    else
      hipLaunchKernelGGL((k_edge_fast<false>), dim3(1024), dim3(512), 0, stream,
          hE, nullptr, Eidx, outVb, hvW11, W11,B11, W12,B12, W13,B13, LG3,LB3, outE);
  } else {
    hipLaunchKernelGGL((k_ffn<false>), dim3(256), dim3(512), 0, stream,
        x1b, Win,Bin, Wout,Bout, W11, LG2,LB2, mV, outV, nullptr, nullptr);
    hipLaunchKernelGGL(k_edge_safe, dim3(1024), dim3(512), 0, stream,
        hE, Eidx, outV, W11,B11, W12,B12, W13,B13, LG3,LB3, outE);
  }
}

// Round 17
// 288.839 us; speedup vs baseline: 1.2239x; 1.0625x over previous
//
#include <hip/hip_runtime.h>
#include <stdint.h>

// DecLayer: ProteinMPNN-style decoder layer. B=4,N=2048,K=48,H=IN=128.
// R17 = R16 + (a) fixed hEb guard (96MB table -> ws>=102MB; R16's 54MB guard
// was wrong, run proved ws>=102MB), (b) weight-fragment streaming: k_wpk packs
// W2/W3/W12/W13/W11[256:384) frags (identical tid->(col,g) math as consumers);
// k_node/k_edge keep only ONE persistent weight set (16 AGPR) and reload the
// rest per phase via opaque-index loads (defeats LICM) -> reg total <=128 ->
// 2 blocks/CU. Bit-identical numerics; ws<103MB falls back to R16 exactly.

typedef __attribute__((ext_vector_type(8))) short bf16x8;
typedef __attribute__((ext_vector_type(4))) float f32x4;
typedef __attribute__((ext_vector_type(4))) float vf4;
typedef __attribute__((ext_vector_type(2))) float vf2;
typedef __attribute__((ext_vector_type(4))) unsigned int vu4;

#define MFMA16(a,b,c) __builtin_amdgcn_mfma_f32_16x16x32_bf16((a),(b),(c),0,0,0)
#define PITCH 17   // uint4 per tile row (272B)

__device__ __forceinline__ float bf2f(uint16_t u){
  union { uint32_t i; float f; } v; v.i = ((uint32_t)u) << 16; return v.f;
}
__device__ __forceinline__ uint32_t cvtpk(float lo, float hi){
  uint32_t r; asm("v_cvt_pk_bf16_f32 %0, %1, %2" : "=v"(r) : "v"(lo), "v"(hi));
  return r;
}
__device__ __forceinline__ uint16_t f2bf1(float x){ return (uint16_t)cvtpk(x, x); }
__device__ __forceinline__ uint4 pk8v(vf4 a, vf4 b){
  uint4 v; v.x=cvtpk(a[0],a[1]); v.y=cvtpk(a[2],a[3]);
  v.z=cvtpk(b[0],b[1]); v.w=cvtpk(b[2],b[3]); return v;
}
__device__ __forceinline__ float geluf(float x){
  float u = 0.7978845608028654f * x * fmaf(0.044715f, x*x, 1.0f);
  float e = __builtin_amdgcn_exp2f(2.8853900817779268f * u);
  float r = __builtin_amdgcn_rcpf(1.0f + e);
  return fmaf(-x, r, x);
}
template<int CTRL>
__device__ __forceinline__ float dpp_add(float x){
  int s = __builtin_amdgcn_update_dpp(0, __builtin_bit_cast(int, x), CTRL, 0xF, 0xF, true);
  return x + __builtin_bit_cast(float, s);
}
__device__ __forceinline__ float red16(float x){
  x = dpp_add<0x121>(x); x = dpp_add<0x122>(x);
  x = dpp_add<0x124>(x); x = dpp_add<0x128>(x);
  return x;
}
__device__ __forceinline__ bf16x8 wfragf(const float* __restrict__ W, int ncols,
                                         int k0, int col, int g){
  const float* p = W + (size_t)(k0 + g*8)*ncols + col;
  bf16x8 f;
#pragma unroll
  for (int j=0;j<8;j++) f[j] = (short)f2bf1(p[j*ncols]);
  return f;
}
// streamed weight-frag load; opaque index defeats LICM so loads stay per-phase
__device__ __forceinline__ void ldwf(bf16x8* dst, const uint4* __restrict__ wpk,
                                     int layer, int tid){
#pragma unroll
  for (int s=0;s<4;s++){
    int idx = (layer*4 + s)*512 + tid;
    asm volatile("" : "+v"(idx));
    dst[s] = __builtin_bit_cast(bf16x8, wpk[idx]);
  }
}
__device__ __forceinline__ bf16x8 afrag(const uint4* tile, int row, int s, int g){
  return *(const bf16x8*)&tile[row*PITCH + 4*s + g];
}
__device__ __forceinline__ void st_m(uint4* tile, int row, int col, uint16_t val){
  ((uint16_t*)tile)[row*(PITCH*8) + col] = val;
}

// ---------------- kernel 0a: hvW1 = bf16(hV) @ bf16(W1[0:128,:]) ---------------
__global__ __launch_bounds__(512) void k_pre(
  const float* __restrict__ hV, const float* __restrict__ W1,
  float* __restrict__ hvW1)
{
  const int tid = threadIdx.x;
  const int w = tid>>6, lane = tid&63, g = lane>>4, l15 = lane&15;
  const int col = w*16 + l15;
  const int node0 = blockIdx.x*16;
  bf16x8 Wf[4], A[4];
#pragma unroll
  for (int s=0;s<4;s++) Wf[s] = wfragf(W1,128,32*s,col,g);
#pragma unroll
  for (int s=0;s<4;s++){
    const float* p = hV + (size_t)(node0 + l15)*128 + 32*s + 8*g;
    uint4 t = pk8v(*(const vf4*)p, *(const vf4*)(p+4));
    A[s] = __builtin_bit_cast(bf16x8, t);
  }
  f32x4 acc = {0,0,0,0};
#pragma unroll
  for (int s=0;s<4;s++) acc = MFMA16(A[s], Wf[s], acc);
#pragma unroll
  for (int r=0;r<4;r++) hvW1[(size_t)(node0 + 4*g + r)*128 + col] = acc[r];
}

// ---------------- kernel 0b: pack streamed weight frags ------------------------
// layers: 0=W2 1=W3 2=W12 3=W13 4=W11[256:384)
__global__ __launch_bounds__(512) void k_wpk(
  const float* __restrict__ W2, const float* __restrict__ W3,
  const float* __restrict__ W12, const float* __restrict__ W13,
  const float* __restrict__ W11, uint4* __restrict__ wpk)
{
  const int tid = threadIdx.x;
  const int w = tid>>6, lane = tid&63, g = lane>>4, l15 = lane&15;
  const int col = w*16 + l15;
  const float* Ws[5] = {W2, W3, W12, W13, W11};
  const int k0s[5] = {0, 0, 0, 0, 256};
#pragma unroll
  for (int l=0;l<5;l++)
#pragma unroll
    for (int s=0;s<4;s++)
      wpk[(size_t)((l*4+s)*512 + tid)] =
          __builtin_bit_cast(uint4, wfragf(Ws[l],128,k0s[l]+32*s,col,g));
}

// ---------------- kernel 1: edge-message MLP + masked sum + LN1 ----------------
template<bool WPK>
__global__ __launch_bounds__(512) void k_node(
  const float* __restrict__ hV, const float* __restrict__ hE,
  const float* __restrict__ mAtt, const float* __restrict__ hvW1,
  const float* __restrict__ W1, const float* __restrict__ B1,
  const float* __restrict__ W2, const float* __restrict__ B2,
  const float* __restrict__ W3, const float* __restrict__ B3,
  const float* __restrict__ LG1, const float* __restrict__ LB1,
  const uint4* __restrict__ wpk,
  uint16_t* __restrict__ x1b, uint16_t* __restrict__ hEb)
{
  __shared__ uint4 Ab[2][48*PITCH];
  __shared__ uint4 Cb[48*PITCH];
  __shared__ float maskb[48];
  __shared__ float dhb[128];

  const int tid = threadIdx.x;
  const int w = tid >> 6, lane = tid & 63, g = lane >> 4, l15 = lane & 15;
  const int col = w*16 + l15;
  const int row0 = tid>>4, cir = tid&15, row1 = 32 + (tid>>4);

  bf16x8 W1e[4];                        // only persistent weight set
#pragma unroll
  for (int s=0;s<4;s++) W1e[s] = wfragf(W1,128,128+32*s,col,g);
  bf16x8 W2p[4], W3p[4];
  if constexpr(!WPK){
#pragma unroll
    for (int s=0;s<4;s++) W2p[s] = wfragf(W2,128,32*s,col,g);
#pragma unroll
    for (int s=0;s<4;s++) W3p[s] = wfragf(W3,128,32*s,col,g);
  }
  const float b1c = B1[col], b2c = B2[col], b3c = B3[col];
  float lg0 = 0, lg1 = 0, lb0 = 0, lb1 = 0;
  if (tid < 64){ lg0 = LG1[2*tid]; lg1 = LG1[2*tid+1]; lb0 = LB1[2*tid]; lb1 = LB1[2*tid+1]; }

  vf4 sr0, sr1, sr2, sr3; float mk = 0.f, hv1;
  {
    const int node = blockIdx.x*8;
    const float* hb = hE + (size_t)node*6144;
    sr0 = __builtin_nontemporal_load((const vf4*)(hb + tid*8));
    sr1 = __builtin_nontemporal_load((const vf4*)(hb + tid*8 + 4));
    if (tid < 256){
      sr2 = __builtin_nontemporal_load((const vf4*)(hb + 4096 + tid*8));
      sr3 = __builtin_nontemporal_load((const vf4*)(hb + 4096 + tid*8 + 4));
    }
    if (tid >= 64 && tid < 112) mk = mAtt[(size_t)node*48 + (tid-64)];
    hv1 = hvW1[(size_t)node*128 + col];
    uint4 v0 = pk8v(sr0, sr1);
    Ab[0][row0*PITCH + cir] = v0;
    if (hEb)
      __builtin_nontemporal_store(*(vu4*)&v0, (vu4*)hEb + (size_t)node*768 + tid);
    if (tid < 256){
      uint4 v1 = pk8v(sr2, sr3);
      Ab[0][row1*PITCH + cir] = v1;
      if (hEb)
        __builtin_nontemporal_store(*(vu4*)&v1, (vu4*)hEb + (size_t)node*768 + 512 + tid);
    }
    if (tid >= 64 && tid < 112) maskb[tid-64] = mk;
  }
  __syncthreads();

  for (int it=0; it<8; ++it){
    const int node = blockIdx.x*8 + it;
    const uint4* Ac = Ab[it&1];
    uint4* Acm = Ab[it&1];
    uint4* An  = Ab[(it&1)^1];
    // ---------- layer 1 ----------
    f32x4 ahv = {hv1, hv1, hv1, hv1};
#pragma unroll
    for (int t=0;t<3;t++){
      f32x4 acc = ahv;
      int row = 16*t + l15;
#pragma unroll
      for (int s=0;s<4;s++) acc = MFMA16(afrag(Ac,row,s,g), W1e[s], acc);
#pragma unroll
      for (int r=0;r<4;r++) st_m(Cb, 16*t+4*g+r, col, f2bf1(geluf(acc[r]+b1c)));
    }
    __syncthreads();
    // ---------- layer 2 ----------
    {
      bf16x8 W2f[4];
      if constexpr(WPK) ldwf(W2f, wpk, 0, tid);
      else { 
#pragma unroll
        for (int s=0;s<4;s++) W2f[s] = W2p[s]; }
#pragma unroll
      for (int t=0;t<3;t++){
        f32x4 acc = {0,0,0,0};
        int row = 16*t + l15;
#pragma unroll
        for (int s=0;s<4;s++) acc = MFMA16(afrag(Cb,row,s,g), W2f[s], acc);
#pragma unroll
        for (int r=0;r<4;r++) st_m(Acm, 16*t+4*g+r, col, f2bf1(geluf(acc[r]+b2c)));
      }
    }
    __syncthreads();
    // ---------- layer 3 + masked sum; issue next-node loads first ----------
    if (it < 7){
      const float* hb = hE + (size_t)(node+1)*6144;
      sr0 = __builtin_nontemporal_load((const vf4*)(hb + tid*8));
      sr1 = __builtin_nontemporal_load((const vf4*)(hb + tid*8 + 4));
      if (tid < 256){
        sr2 = __builtin_nontemporal_load((const vf4*)(hb + 4096 + tid*8));
        sr3 = __builtin_nontemporal_load((const vf4*)(hb + 4096 + tid*8 + 4));
      }
      if (tid >= 64 && tid < 112) mk = mAtt[(size_t)(node+1)*48 + (tid-64)];
      hv1 = hvW1[(size_t)(node+1)*128 + col];
    }
    {
      bf16x8 W3f[4];
      if constexpr(WPK) ldwf(W3f, wpk, 1, tid);
      else { 
#pragma unroll
        for (int s=0;s<4;s++) W3f[s] = W3p[s]; }
      float pp = 0.f;
#pragma unroll
      for (int t=0;t<3;t++){
        f32x4 acc = {0,0,0,0};
        int row = 16*t + l15;
#pragma unroll
        for (int s=0;s<4;s++) acc = MFMA16(afrag(Ac,row,s,g), W3f[s], acc);
#pragma unroll
        for (int r=0;r<4;r++) pp += maskb[16*t+4*g+r] * (acc[r] + b3c);
      }
      pp += __shfl_xor(pp, 16);
      pp += __shfl_xor(pp, 32);
      if (lane < 16) dhb[col] = pp * (1.f/30.f);
    }
    __syncthreads();
    // ---------- LN1 (wave 0) + stage next node ----------
    if (tid < 64){
      int c0 = 2*tid, c1 = c0+1;
      float2 hv2 = *(const float2*)(hV + (size_t)node*128 + c0);
      float xa = hv2.x + dhb[c0];
      float xc = hv2.y + dhb[c1];
      float s1 = xa + xc, s2 = xa*xa + xc*xc;
      s1 = red16(s1); s2 = red16(s2);
      s1 += __shfl_xor(s1,16); s2 += __shfl_xor(s2,16);
      s1 += __shfl_xor(s1,32); s2 += __shfl_xor(s2,32);
      float mu = s1 * (1.0f/128.0f);
      float var = fmaxf(s2 * (1.0f/128.0f) - mu*mu, 0.f);
      float rstd = __builtin_amdgcn_rsqf(var + 1e-5f);
      float ya = (xa-mu)*rstd*lg0 + lb0;
      float yc = (xc-mu)*rstd*lg1 + lb1;
      ((uint32_t*)x1b)[(size_t)node*64 + tid] = cvtpk(ya, yc);
    }
    if (it < 7){
      uint4 v0 = pk8v(sr0, sr1);
      An[row0*PITCH + cir] = v0;
      if (hEb)
        __builtin_nontemporal_store(*(vu4*)&v0, (vu4*)hEb + (size_t)(node+1)*768 + tid);
      if (tid < 256){
        uint4 v1 = pk8v(sr2, sr3);
        An[row1*PITCH + cir] = v1;
        if (hEb)
          __builtin_nontemporal_store(*(vu4*)&v1, (vu4*)hEb + (size_t)(node+1)*768 + 512 + tid);
      }
      if (tid >= 64 && tid < 112) maskb[tid-64] = mk;
    }
    __syncthreads();
  }
}

// ---------------- kernel 2: fused FFN + LN2 + mask_V (+ optional hvW11) --------
template<bool HV11>
__global__ __launch_bounds__(512) void k_ffn(
  const uint16_t* __restrict__ x1b,
  const float* __restrict__ Win, const float* __restrict__ Bin,
  const float* __restrict__ Wout, const float* __restrict__ Bout,
  const float* __restrict__ W11,
  const float* __restrict__ LG2, const float* __restrict__ LB2,
  const float* __restrict__ maskV,
  float* __restrict__ outV, uint16_t* __restrict__ outVb,
  float* __restrict__ hvW11)
{
  __shared__ uint4 lh[16*65];
  __shared__ float xb[16*129];

  const int tid = threadIdx.x;
  const int w = tid>>6, lane = tid&63, g = lane>>4, l15 = lane&15;
  const int colo = w*16 + l15;

  bf16x8 WiF[4][4], WoF[16], W11s[4];
#pragma unroll
  for (int s=0;s<4;s++)
#pragma unroll
    for (int c=0;c<4;c++) WiF[s][c] = wfragf(Win,512,32*s, w*64 + c*16 + l15, g);
#pragma unroll
  for (int s=0;s<16;s++) WoF[s] = wfragf(Wout,128,32*s, colo, g);
  if (HV11){
#pragma unroll
    for (int s=0;s<4;s++) W11s[s] = wfragf(W11,128,32*s,colo,g);
  }
  float binc[4];
#pragma unroll
  for (int c=0;c<4;c++) binc[c] = Bin[w*64 + c*16 + l15];
  const float boutc = Bout[colo];
  const float lg0 = LG2[2*lane], lg1 = LG2[2*lane+1];
  const float lb0 = LB2[2*lane], lb1 = LB2[2*lane+1];

  for (int it=0; it<2; ++it){
    const int node0 = (blockIdx.x*2 + it)*16;
    bf16x8 A[4];
#pragma unroll
    for (int s=0;s<4;s++) A[s] = *(const bf16x8*)(x1b + (size_t)(node0 + l15)*128 + 32*s + 8*g);
#pragma unroll
    for (int c=0;c<4;c++){
      f32x4 acc = {0,0,0,0};
#pragma unroll
      for (int s=0;s<4;s++) acc = MFMA16(A[s], WiF[s][c], acc);
      int colh = w*64 + c*16 + l15;
#pragma unroll
      for (int r=0;r<4;r++){
        int row = 4*g + r;
        ((uint16_t*)lh)[row*(65*8) + colh] = f2bf1(geluf(acc[r] + binc[c]));
      }
    }
    __syncthreads();
    f32x4 acc = {0,0,0,0};
#pragma unroll
    for (int s=0;s<16;s++){
      bf16x8 a = *(const bf16x8*)&lh[l15*65 + 4*s + g];
      acc = MFMA16(a, WoF[s], acc);
    }
#pragma unroll
    for (int r=0;r<4;r++){
      int row = 4*g + r;
      xb[row*129 + colo] = bf2f(x1b[(size_t)(node0+row)*128 + colo]) + acc[r] + boutc;
    }
    __syncthreads();
#pragma unroll
    for (int rr=0; rr<2; ++rr){
      int row = w + rr*8;
      int c0 = 2*lane;
      float xa = xb[row*129 + c0], xc = xb[row*129 + c0 + 1];
      float s1 = xa + xc, s2 = xa*xa + xc*xc;
      s1 = red16(s1); s2 = red16(s2);
      s1 += __shfl_xor(s1,16); s2 += __shfl_xor(s2,16);
      s1 += __shfl_xor(s1,32); s2 += __shfl_xor(s2,32);
      float mu = s1*(1.0f/128.0f);
      float var = fmaxf(s2*(1.0f/128.0f)-mu*mu, 0.f);
      float rstd = __builtin_amdgcn_rsqf(var + 1e-5f);
      float mv = maskV[node0 + row];
      float ya = ((xa-mu)*rstd*lg0 + lb0) * mv;
      float yc = ((xc-mu)*rstd*lg1 + lb1) * mv;
      vf2 o2; o2[0] = ya; o2[1] = yc;
      __builtin_nontemporal_store(o2, (vf2*)outV + (size_t)(node0+row)*64 + lane);
      uint32_t pk = cvtpk(ya, yc);
      if (outVb)
        ((uint32_t*)outVb)[(size_t)(node0+row)*64 + lane] = pk;
      if (HV11)
        ((uint32_t*)lh)[row*132 + lane] = pk;
    }
    __syncthreads();
    if (HV11){
      f32x4 a2 = {0,0,0,0};
#pragma unroll
      for (int s=0;s<4;s++){
        bf16x8 a = *(const bf16x8*)&((uint32_t*)lh)[l15*132 + 16*s + 4*g];
        a2 = MFMA16(a, W11s[s], a2);
      }
#pragma unroll
      for (int r=0;r<4;r++)
        hvW11[(size_t)(node0 + 4*g + r)*128 + colo] = a2[r];
      __syncthreads();
    }
  }
}

// ---------------- kernel 3 (fast): edge update MLP + LN3 ----------------
template<bool HEB, bool WPK>
__global__ __launch_bounds__(512) void k_edge_fast(
  const float* __restrict__ hE, const uint16_t* __restrict__ hEb,
  const int* __restrict__ Eidx,
  const uint16_t* __restrict__ hV2b, const float* __restrict__ hvW11,
  const uint4* __restrict__ wpk,
  const float* __restrict__ W11, const float* __restrict__ B11,
  const float* __restrict__ W12, const float* __restrict__ B12,
  const float* __restrict__ W13, const float* __restrict__ B13,
  const float* __restrict__ LG3, const float* __restrict__ LB3,
  float* __restrict__ outE)
{
  __shared__ uint4 Ab[2][48*PITCH];
  __shared__ uint4 Bb[48*PITCH];
  __shared__ uint4 Cb[48*PITCH];

  const int tid = threadIdx.x;
  const int w = tid>>6, lane = tid&63, g = lane>>4, l15 = lane&15;
  const int col = w*16 + l15;
  const int row0 = tid>>4, cir = tid&15, row1 = 32 + (tid>>4);

  bf16x8 W11e[4];                       // only persistent weight set
#pragma unroll
  for (int s=0;s<4;s++) W11e[s] = wfragf(W11,128, 128+32*s,col,g);
  bf16x8 W11np[4], W12p[4], W13p[4];
  if constexpr(!WPK){
#pragma unroll
    for (int s=0;s<4;s++) W11np[s] = wfragf(W11,128, 256+32*s,col,g);
#pragma unroll
    for (int s=0;s<4;s++) W12p[s]  = wfragf(W12,128,     32*s,col,g);
#pragma unroll
    for (int s=0;s<4;s++) W13p[s]  = wfragf(W13,128,     32*s,col,g);
  }
  const float b11c = B11[col], b12c = B12[col], b13c = B13[col];
  const float lg0 = LG3[2*lane], lg1 = LG3[2*lane+1];
  const float lb0 = LB3[2*lane], lb1 = LB3[2*lane+1];

  vf4 sr0, sr1, sr2, sr3; vu4 su0, su1;
  int gi0, gi1; float hv11;
  {
    const int node = blockIdx.x*8;
    const int bb = (node >> 11) << 11;
    if (HEB){
      su0 = __builtin_nontemporal_load((const vu4*)hEb + (size_t)node*768 + tid);
      if (tid < 256)
        su1 = __builtin_nontemporal_load((const vu4*)hEb + (size_t)node*768 + 512 + tid);
    } else {
      const float* hb = hE + (size_t)node*6144;
      sr0 = __builtin_nontemporal_load((const vf4*)(hb + tid*8));
      sr1 = __builtin_nontemporal_load((const vf4*)(hb + tid*8 + 4));
      if (tid < 256){
        sr2 = __builtin_nontemporal_load((const vf4*)(hb + 4096 + tid*8));
        sr3 = __builtin_nontemporal_load((const vf4*)(hb + 4096 + tid*8 + 4));
      }
    }
    gi0 = Eidx[(size_t)node*48 + (tid>>4)];
    gi1 = (tid < 256) ? Eidx[(size_t)node*48 + 32 + (tid>>4)] : 0;
    hv11 = hvW11[(size_t)node*128 + col];
    uint4 gq0 = *(const uint4*)(hV2b + (size_t)(bb + gi0)*128 + (tid&15)*8);
    uint4 gq1;
    if (tid < 256) gq1 = *(const uint4*)(hV2b + (size_t)(bb + gi1)*128 + (tid&15)*8);
    if (HEB){
      *(vu4*)&Ab[0][row0*PITCH + cir] = su0;
      if (tid < 256) *(vu4*)&Ab[0][row1*PITCH + cir] = su1;
    } else {
      Ab[0][row0*PITCH + cir] = pk8v(sr0, sr1);
      if (tid < 256) Ab[0][row1*PITCH + cir] = pk8v(sr2, sr3);
    }
    Bb[row0*PITCH + cir] = gq0;
    if (tid < 256) Bb[row1*PITCH + cir] = gq1;
  }
  __syncthreads();

  for (int it=0; it<8; ++it){
    const int node = blockIdx.x*8 + it;
    const uint4* Ac = Ab[it&1];
    uint4* An = Ab[(it&1)^1];
    // ---------- layer 1: Ab[cur] + Bb -> Cb (acc init = hvW11) ----------
    {
      bf16x8 W11n[4];
      if constexpr(WPK) ldwf(W11n, wpk, 4, tid);
      else { 
#pragma unroll
        for (int s=0;s<4;s++) W11n[s] = W11np[s]; }
      f32x4 ahv = {hv11, hv11, hv11, hv11};
#pragma unroll
      for (int t=0;t<3;t++){
        f32x4 acc = ahv;
        int row = 16*t + l15;
#pragma unroll
        for (int s=0;s<4;s++) acc = MFMA16(afrag(Ac,row,s,g), W11e[s], acc);
#pragma unroll
        for (int s=0;s<4;s++) acc = MFMA16(afrag(Bb,row,s,g), W11n[s], acc);
#pragma unroll
        for (int r=0;r<4;r++) st_m(Cb, 16*t+4*g+r, col, f2bf1(geluf(acc[r]+b11c)));
      }
    }
    __syncthreads();
    // ---------- layer 2: Cb -> Bb ----------
    {
      bf16x8 W12f[4];
      if constexpr(WPK) ldwf(W12f, wpk, 2, tid);
      else { 
#pragma unroll
        for (int s=0;s<4;s++) W12f[s] = W12p[s]; }
#pragma unroll
      for (int t=0;t<3;t++){
        f32x4 acc = {0,0,0,0};
        int row = 16*t + l15;
#pragma unroll
        for (int s=0;s<4;s++) acc = MFMA16(afrag(Cb,row,s,g), W12f[s], acc);
#pragma unroll
        for (int r=0;r<4;r++) st_m(Bb, 16*t+4*g+r, col, f2bf1(geluf(acc[r]+b12c)));
      }
    }
    __syncthreads();
    // ---------- layer 3: Bb -> Cb; issue next loads first ----------
    if (it < 7){
      if (HEB){
        su0 = __builtin_nontemporal_load((const vu4*)hEb + (size_t)(node+1)*768 + tid);
        if (tid < 256)
          su1 = __builtin_nontemporal_load((const vu4*)hEb + (size_t)(node+1)*768 + 512 + tid);
      } else {
        const float* hb = hE + (size_t)(node+1)*6144;
        sr0 = __builtin_nontemporal_load((const vf4*)(hb + tid*8));
        sr1 = __builtin_nontemporal_load((const vf4*)(hb + tid*8 + 4));
        if (tid < 256){
          sr2 = __builtin_nontemporal_load((const vf4*)(hb + 4096 + tid*8));
          sr3 = __builtin_nontemporal_load((const vf4*)(hb + 4096 + tid*8 + 4));
        }
      }
      gi0 = Eidx[(size_t)(node+1)*48 + (tid>>4)];
      gi1 = (tid < 256) ? Eidx[(size_t)(node+1)*48 + 32 + (tid>>4)] : 0;
      hv11 = hvW11[(size_t)(node+1)*128 + col];
    }
    {
      bf16x8 W13f[4];
      if constexpr(WPK) ldwf(W13f, wpk, 3, tid);
      else { 
#pragma unroll
        for (int s=0;s<4;s++) W13f[s] = W13p[s]; }
#pragma unroll
      for (int t=0;t<3;t++){
        f32x4 acc = {0,0,0,0};
        int row = 16*t + l15;
#pragma unroll
        for (int s=0;s<4;s++) acc = MFMA16(afrag(Bb,row,s,g), W13f[s], acc);
#pragma unroll
        for (int r=0;r<4;r++) st_m(Cb, 16*t+4*g+r, col, f2bf1(acc[r]+b13c));
      }
    }
    __syncthreads();
    // ---------- LN3 (+ issue gathers, then stage next node) ----------
    uint4 gq0, gq1;
    if (it < 7){
      const int bb2 = ((node+1) >> 11) << 11;
      gq0 = *(const uint4*)(hV2b + (size_t)(bb2 + gi0)*128 + (tid&15)*8);
      if (tid < 256) gq1 = *(const uint4*)(hV2b + (size_t)(bb2 + gi1)*128 + (tid&15)*8);
    }
#pragma unroll
    for (int rr=0; rr<6; ++rr){
      int row = w + rr*8;
      uint32_t pe = ((const uint32_t*)Ac)[row*(PITCH*4) + lane];
      uint32_t pv = ((const uint32_t*)Cb)[row*(PITCH*4) + lane];
      float xa = bf2f((uint16_t)(pe & 0xffff)) + bf2f((uint16_t)(pv & 0xffff));
      float xc = bf2f((uint16_t)(pe >> 16))    + bf2f((uint16_t)(pv >> 16));
      float s1 = xa + xc, s2 = xa*xa + xc*xc;
      s1 = red16(s1); s2 = red16(s2);
      s1 += __shfl_xor(s1,16); s2 += __shfl_xor(s2,16);
      s1 += __shfl_xor(s1,32); s2 += __shfl_xor(s2,32);
      float mu = s1*(1.0f/128.0f);
      float var = fmaxf(s2*(1.0f/128.0f)-mu*mu, 0.f);
      float rstd = __builtin_amdgcn_rsqf(var+1e-5f);
      float ya = (xa-mu)*rstd*lg0 + lb0;
      float yc = (xc-mu)*rstd*lg1 + lb1;
      vf2 o2; o2[0] = ya; o2[1] = yc;
      __builtin_nontemporal_store(o2, (vf2*)outE + ((size_t)node*48 + row)*64 + lane);
    }
    if (it < 7){
      if (HEB){
        *(vu4*)&An[row0*PITCH + cir] = su0;
        if (tid < 256) *(vu4*)&An[row1*PITCH + cir] = su1;
      } else {
        An[row0*PITCH + cir] = pk8v(sr0, sr1);
        if (tid < 256) An[row1*PITCH + cir] = pk8v(sr2, sr3);
      }
      Bb[row0*PITCH + cir] = gq0;
      if (tid < 256) Bb[row1*PITCH + cir] = gq1;
    }
    __syncthreads();
  }
}

// ---------------- kernel 3 (safe fallback) ----------------
__global__ __launch_bounds__(512) void k_edge_safe(
  const float* __restrict__ hE, const int* __restrict__ Eidx,
  const float* __restrict__ hV2f,
  const float* __restrict__ W11, const float* __restrict__ B11,
  const float* __restrict__ W12, const float* __restrict__ B12,
  const float* __restrict__ W13, const float* __restrict__ B13,
  const float* __restrict__ LG3, const float* __restrict__ LB3,
  float* __restrict__ outE)
{
  __shared__ uint4 Ab[2][48*PITCH];
  __shared__ uint4 Bb[48*PITCH];
  __shared__ uint4 Cb[48*PITCH];
  __shared__ uint4 hvb[16];

  const int tid = threadIdx.x;
  const int w = tid>>6, lane = tid&63, g = lane>>4, l15 = lane&15;
  const int col = w*16 + l15;
  const int row0 = tid>>4, cir = tid&15, row1 = 32 + (tid>>4);

  bf16x8 Ws[4], W11e[4], W11n[4], W12f[4], W13f[4];
#pragma unroll
  for (int s=0;s<4;s++) Ws[s]   = wfragf(W11,128,     32*s,col,g);
#pragma unroll
  for (int s=0;s<4;s++) W11e[s] = wfragf(W11,128, 128+32*s,col,g);
#pragma unroll
  for (int s=0;s<4;s++) W11n[s] = wfragf(W11,128, 256+32*s,col,g);
#pragma unroll
  for (int s=0;s<4;s++) W12f[s] = wfragf(W12,128,     32*s,col,g);
#pragma unroll
  for (int s=0;s<4;s++) W13f[s] = wfragf(W13,128,     32*s,col,g);
  const float b11c = B11[col], b12c = B12[col], b13c = B13[col];

  vf4 sr0, sr1, sr2, sr3; int gi0, gi1; uint4 hvr;
  {
    const int node = blockIdx.x*8;
    const int bb = (node >> 11) << 11;
    const float* hb = hE + (size_t)node*6144;
    sr0 = __builtin_nontemporal_load((const vf4*)(hb + tid*8));
    sr1 = __builtin_nontemporal_load((const vf4*)(hb + tid*8 + 4));
    if (tid < 256){
      sr2 = __builtin_nontemporal_load((const vf4*)(hb + 4096 + tid*8));
      sr3 = __builtin_nontemporal_load((const vf4*)(hb + 4096 + tid*8 + 4));
    }
    gi0 = Eidx[(size_t)node*48 + (tid>>4)];
    gi1 = (tid < 256) ? Eidx[(size_t)node*48 + 32 + (tid>>4)] : 0;
    uint4 gq0, gq1;
    {
      const float* p0 = hV2f + (size_t)(bb + gi0)*128 + (tid&15)*8;
      gq0 = pk8v(*(const vf4*)p0, *(const vf4*)(p0+4));
      if (tid < 256){
        const float* p1 = hV2f + (size_t)(bb + gi1)*128 + (tid&15)*8;
        gq1 = pk8v(*(const vf4*)p1, *(const vf4*)(p1+4));
      }
      if (tid < 16){
        const float* p = hV2f + (size_t)node*128 + tid*8;
        hvr = pk8v(*(const vf4*)p, *(const vf4*)(p+4));
      }
    }
    Ab[0][row0*PITCH + cir] = pk8v(sr0, sr1);
    Bb[row0*PITCH + cir] = gq0;
    if (tid < 256){
      Ab[0][row1*PITCH + cir] = pk8v(sr2, sr3);
      Bb[row1*PITCH + cir] = gq1;
    }
    if (tid < 16) hvb[tid] = hvr;
  }
  __syncthreads();

  for (int it=0; it<8; ++it){
    const int node = blockIdx.x*8 + it;
    const uint4* Ac = Ab[it&1];
    uint4* An = Ab[(it&1)^1];
    f32x4 ahv = {0,0,0,0};
#pragma unroll
    for (int s=0;s<4;s++) ahv = MFMA16(*(const bf16x8*)&hvb[4*s+g], Ws[s], ahv);
#pragma unroll
    for (int t=0;t<3;t++){
      f32x4 acc = ahv;
      int row = 16*t + l15;
#pragma unroll
      for (int s=0;s<4;s++) acc = MFMA16(afrag(Ac,row,s,g), W11e[s], acc);
#pragma unroll
      for (int s=0;s<4;s++) acc = MFMA16(afrag(Bb,row,s,g), W11n[s], acc);
#pragma unroll
      for (int r=0;r<4;r++) st_m(Cb, 16*t+4*g+r, col, f2bf1(geluf(acc[r]+b11c)));
    }
    __syncthreads();
#pragma unroll
    for (int t=0;t<3;t++){
      f32x4 acc = {0,0,0,0};
      int row = 16*t + l15;
#pragma unroll
      for (int s=0;s<4;s++) acc = MFMA16(afrag(Cb,row,s,g), W12f[s], acc);
#pragma unroll
      for (int r=0;r<4;r++) st_m(Bb, 16*t+4*g+r, col, f2bf1(geluf(acc[r]+b12c)));
    }
    __syncthreads();
    if (it < 7){
      const float* hb = hE + (size_t)(node+1)*6144;
      sr0 = __builtin_nontemporal_load((const vf4*)(hb + tid*8));
      sr1 = __builtin_nontemporal_load((const vf4*)(hb + tid*8 + 4));
      if (tid < 256){
        sr2 = __builtin_nontemporal_load((const vf4*)(hb + 4096 + tid*8));
        sr3 = __builtin_nontemporal_load((const vf4*)(hb + 4096 + tid*8 + 4));
      }
      gi0 = Eidx[(size_t)(node+1)*48 + (tid>>4)];
      gi1 = (tid < 256) ? Eidx[(size_t)(node+1)*48 + 32 + (tid>>4)] : 0;
    }
#pragma unroll
    for (int t=0;t<3;t++){
      f32x4 acc = {0,0,0,0};
      int row = 16*t + l15;
#pragma unroll
      for (int s=0;s<4;s++) acc = MFMA16(afrag(Bb,row,s,g), W13f[s], acc);
#pragma unroll
      for (int r=0;r<4;r++) st_m(Cb, 16*t+4*g+r, col, f2bf1(acc[r]+b13c));
    }
    __syncthreads();
    uint4 gq0, gq1;
    if (it < 7){
      const int bb2 = ((node+1) >> 11) << 11;
      const float* p0 = hV2f + (size_t)(bb2 + gi0)*128 + (tid&15)*8;
      gq0 = pk8v(*(const vf4*)p0, *(const vf4*)(p0+4));
      if (tid < 256){
        const float* p1 = hV2f + (size_t)(bb2 + gi1)*128 + (tid&15)*8;
        gq1 = pk8v(*(const vf4*)p1, *(const vf4*)(p1+4));
      }
      if (tid < 16){
        const float* p = hV2f + (size_t)(node+1)*128 + tid*8;
        hvr = pk8v(*(const vf4*)p, *(const vf4*)(p+4));
      }
    }
#pragma unroll
    for (int rr=0; rr<6; ++rr){
      int row = w + rr*8;
      int c0 = 2*lane;
      uint32_t pe = ((const uint32_t*)Ac)[row*(PITCH*4) + lane];
      uint32_t pv = ((const uint32_t*)Cb)[row*(PITCH*4) + lane];
      float xa = bf2f((uint16_t)(pe & 0xffff)) + bf2f((uint16_t)(pv & 0xffff));
      float xc = bf2f((uint16_t)(pe >> 16))    + bf2f((uint16_t)(pv >> 16));
      float s1 = xa + xc, s2 = xa*xa + xc*xc;
      s1 = red16(s1); s2 = red16(s2);
      s1 += __shfl_xor(s1,16); s2 += __shfl_xor(s2,16);
      s1 += __shfl_xor(s1,32); s2 += __shfl_xor(s2,32);
      float mu = s1*(1.0f/128.0f);
      float var = fmaxf(s2*(1.0f/128.0f)-mu*mu, 0.f);
      float rstd = __builtin_amdgcn_rsqf(var+1e-5f);
      float ya = (xa-mu)*rstd*LG3[c0] + LB3[c0];
      float yc = (xc-mu)*rstd*LG3[c0+1] + LB3[c0+1];
      vf2 o2; o2[0] = ya; o2[1] = yc;
      __builtin_nontemporal_store(o2, (vf2*)outE + ((size_t)node*48 + row)*64 + lane);
    }
    if (it < 7){
      An[row0*PITCH + cir] = pk8v(sr0, sr1);
      Bb[row0*PITCH + cir] = gq0;
      if (tid < 256){
        An[row1*PITCH + cir] = pk8v(sr2, sr3);
        Bb[row1*PITCH + cir] = gq1;
      }
      if (tid < 16) hvb[tid] = hvr;
    }
    __syncthreads();
  }
}

extern "C" void kernel_launch(void* const* d_in, const int* in_sizes, int n_in,
                              void* d_out, int out_size, void* d_ws, size_t ws_size,
                              hipStream_t stream){
  const float* hV   = (const float*)d_in[0];
  const float* hE   = (const float*)d_in[1];
  const float* mV   = (const float*)d_in[2];
  const int*   Eidx = (const int*)d_in[3];
  const float* mAtt = (const float*)d_in[4];
  const float* W1 = (const float*)d_in[5];  const float* B1 = (const float*)d_in[6];
  const float* W2 = (const float*)d_in[7];  const float* B2 = (const float*)d_in[8];
  const float* W3 = (const float*)d_in[9];  const float* B3 = (const float*)d_in[10];
  const float* W11 = (const float*)d_in[11]; const float* B11 = (const float*)d_in[12];
  const float* W12 = (const float*)d_in[13]; const float* B12 = (const float*)d_in[14];
  const float* W13 = (const float*)d_in[15]; const float* B13 = (const float*)d_in[16];
  const float* Win = (const float*)d_in[17]; const float* Bin = (const float*)d_in[18];
  const float* Wout= (const float*)d_in[19]; const float* Bout= (const float*)d_in[20];
  const float* LG1 = (const float*)d_in[21]; const float* LB1 = (const float*)d_in[22];
  const float* LG2 = (const float*)d_in[23]; const float* LB2 = (const float*)d_in[24];
  const float* LG3 = (const float*)d_in[25]; const float* LB3 = (const float*)d_in[26];

  float* outV = (float*)d_out;                     // [B*N*H] f32
  float* outE = outV + (size_t)1048576;            // [B*N*K*IN] f32
  uint16_t* x1b = (uint16_t*)(outE + (size_t)1048576);   // [4,6MB) of outE region
  float*    hvW1 = outE + (size_t)1572864;         // [6,10MB): dead after k_node

  const bool fast  = ws_size >= ((size_t)6<<20);
  const bool bigws = ws_size >= ((size_t)102<<20);   // hEb = 8192 nodes x 12KB = 96MB
  const bool wpkok = ws_size >= ((size_t)103<<20);   // + 160KB wpack
  uint16_t* outVb = fast ? (uint16_t*)d_ws : nullptr;                           // [0,2MB)
  float*    hvW11 = fast ? (float*)((char*)d_ws + ((size_t)2<<20)) : nullptr;   // [2,6MB)
  uint16_t* hEb   = bigws ? (uint16_t*)((char*)d_ws + ((size_t)6<<20)) : nullptr; // [6,102MB)
  uint4*    wpk   = wpkok ? (uint4*)((char*)d_ws + ((size_t)102<<20)) : nullptr;  // [102,102.16MB)

  hipLaunchKernelGGL(k_pre, dim3(512), dim3(512), 0, stream, hV, W1, hvW1);
  if (wpkok)
    hipLaunchKernelGGL(k_wpk, dim3(1), dim3(512), 0, stream, W2, W3, W12, W13, W11, wpk);
  if (wpkok)
    hipLaunchKernelGGL((k_node<true>), dim3(1024), dim3(512), 0, stream,
        hV, hE, mAtt, hvW1, W1,B1, W2,B2, W3,B3, LG1,LB1, wpk, x1b, hEb);
  else
    hipLaunchKernelGGL((k_node<false>), dim3(1024), dim3(512), 0, stream,
        hV, hE, mAtt, hvW1, W1,B1, W2,B2, W3,B3, LG1,LB1, nullptr, x1b, hEb);
  if (fast){
    hipLaunchKernelGGL((k_ffn<true>), dim3(256), dim3(512), 0, stream,
        x1b, Win,Bin, Wout,Bout, W11, LG2,LB2, mV, outV, outVb, hvW11);
    if (wpkok)
      hipLaunchKernelGGL((k_edge_fast<true,true>), dim3(1024), dim3(512), 0, stream,
          hE, hEb, Eidx, outVb, hvW11, wpk, W11,B11, W12,B12, W13,B13, LG3,LB3, outE);
    else if (bigws)
      hipLaunchKernelGGL((k_edge_fast<true,false>), dim3(1024), dim3(512), 0, stream,
          hE, hEb, Eidx, outVb, hvW11, nullptr, W11,B11, W12,B12, W13,B13, LG3,LB3, outE);
    else
      hipLaunchKernelGGL((k_edge_fast<false,false>), dim3(1024), dim3(512), 0, stream,
          hE, nullptr, Eidx, outVb, hvW11, nullptr, W11,B11, W12,B12, W13,B13, LG3,LB3, outE);
  } else {
    hipLaunchKernelGGL((k_ffn<false>), dim3(256), dim3(512), 0, stream,
        x1b, Win,Bin, Wout,Bout, W11, LG2,LB2, mV, outV, nullptr, nullptr);
    hipLaunchKernelGGL(k_edge_safe, dim3(1024), dim3(512), 0, stream,
        hE, Eidx, outV, W11,B11, W12,B12, W13,B13, LG3,LB3, outE);
  }
}